// Round 3
// baseline (666.045 us; speedup 1.0000x reference)
//
#include <hip/hip_runtime.h>
#include <hip/hip_bf16.h>
#include <math.h>

#define T_TOK 16384
#define CC 256
#define PP 16
#define HH 8
#define DD 32
#define LN_EPS 1e-5f
#define CHUNK 2048

typedef __attribute__((ext_vector_type(8))) short bf16x8_t;
typedef __attribute__((ext_vector_type(4))) float f32x4_t;

__device__ __forceinline__ unsigned short f2bf(float x) {
  __hip_bfloat16 h = __float2bfloat16(x);
  return *reinterpret_cast<unsigned short*>(&h);
}
__device__ __forceinline__ float bf2f(unsigned short u) {
  union { unsigned int i; float f; } v; v.i = ((unsigned int)u) << 16; return v.f;
}

// ---------------------------------------------------------------------------
// Prep kernels
// ---------------------------------------------------------------------------
__global__ __launch_bounds__(256) void cvt_bf16_kernel(const float* __restrict__ src,
                                                       unsigned short* __restrict__ dst) {
  int i = (blockIdx.x * 256 + threadIdx.x) * 4;
  float4 v = *(const float4*)&src[i];
  ushort4 o = make_ushort4(f2bf(v.x), f2bf(v.y), f2bf(v.z), f2bf(v.w));
  *(ushort4*)&dst[i] = o;
}

__global__ __launch_bounds__(256) void transpose_cvt_kernel(const float* __restrict__ src,
                                                            unsigned short* __restrict__ dst,
                                                            int K, int N) {
  __shared__ float tile[64][65];
  int k0 = blockIdx.x * 64, n0 = blockIdx.y * 64;
  int tid = threadIdx.x;
#pragma unroll
  for (int i = 0; i < 16; i++) {
    int lin = i * 256 + tid, r = lin >> 6, c = lin & 63;
    tile[r][c] = src[(size_t)(k0 + r) * N + n0 + c];
  }
  __syncthreads();
#pragma unroll
  for (int i = 0; i < 16; i++) {
    int lin = i * 256 + tid, n = lin >> 6, k = lin & 63;
    dst[(size_t)(n0 + n) * K + k0 + k] = f2bf(tile[k][n]);
  }
}

// Mt[(h*256+e)][c] = bf16( sum_d Wq[c][h*32+d] * Wk[e][h*32+d] )
__global__ __launch_bounds__(256) void precM_kernel(const float* __restrict__ Wq,
                                                    const float* __restrict__ Wk,
                                                    unsigned short* __restrict__ Mt) {
  int n = blockIdx.x;
  int h = n >> 8, e = n & 255;
  int c = threadIdx.x;
  const float* wkrow = Wk + (size_t)e * CC + h * DD;
  const float* wqrow = Wq + (size_t)c * CC + h * DD;
  float s = 0.f;
#pragma unroll
  for (int d = 0; d < DD; d++) s += wqrow[d] * wkrow[d];
  Mt[(size_t)n * CC + c] = f2bf(s);
}

// ---------------------------------------------------------------------------
// MFMA GEMM: Out[M,*] = A[M,K] @ Bt^T  (Bt [N][K] bf16), BM=64 BN=256 BK=32.
// Double-buffered LDS + register prefetch: ONE barrier per K-step.
// EPI 0: bf16 store (strideO, col offset n0). EPI 1: LN(g,b) -> bf16.
// ---------------------------------------------------------------------------
template<int EPI>
__global__ __launch_bounds__(512) void mfma_gemm_kernel(
    const unsigned short* __restrict__ A, const unsigned short* __restrict__ Bt,
    unsigned short* __restrict__ Out, const float* __restrict__ gam,
    const float* __restrict__ bet, int K, int strideO) {
  __shared__ __align__(16) unsigned short As[2][64 * 32];
  __shared__ __align__(16) unsigned short Bs[2][256 * 32];
  __shared__ float redS[64][5], redQ[64][5];
  const int tid = threadIdx.x;
  const int wv = tid >> 6, l = tid & 63;
  const int wr = wv >> 2, wc = wv & 3;
  const int lr = l & 15, lq = l >> 4;
  const int m0 = blockIdx.x * 64;
  const int n0 = blockIdx.y * 256;
  const int nsteps = K >> 5;

  f32x4_t acc[2][4];
#pragma unroll
  for (int m = 0; m < 2; m++)
#pragma unroll
    for (int n = 0; n < 4; n++) acc[m][n] = (f32x4_t){0.f, 0.f, 0.f, 0.f};

  uint4 aReg; uint4 bReg[2];
  // stage step 0
  if (tid < 256) {
    int r = tid >> 2, s = tid & 3, q = s ^ ((r >> 1) & 3);
    aReg = *(const uint4*)&A[(size_t)(m0 + r) * K + q * 8];
    *(uint4*)&As[0][r * 32 + s * 8] = aReg;
  }
#pragma unroll
  for (int it = 0; it < 2; it++) {
    int lin = it * 512 + tid, r = lin >> 2, s = lin & 3, q = s ^ ((r >> 1) & 3);
    bReg[it] = *(const uint4*)&Bt[(size_t)(n0 + r) * K + q * 8];
    *(uint4*)&Bs[0][r * 32 + s * 8] = bReg[it];
  }
  __syncthreads();

  for (int st = 0; st < nsteps; st++) {
    int cur = st & 1;
    bool pf = (st + 1) < nsteps;
    if (pf) {
      int kn = (st + 1) * 32;
      if (tid < 256) {
        int r = tid >> 2, s = tid & 3, q = s ^ ((r >> 1) & 3);
        aReg = *(const uint4*)&A[(size_t)(m0 + r) * K + kn + q * 8];
      }
#pragma unroll
      for (int it = 0; it < 2; it++) {
        int lin = it * 512 + tid, r = lin >> 2, s = lin & 3, q = s ^ ((r >> 1) & 3);
        bReg[it] = *(const uint4*)&Bt[(size_t)(n0 + r) * K + kn + q * 8];
      }
    }
    bf16x8_t af[2], bfr[4];
#pragma unroll
    for (int m = 0; m < 2; m++) {
      int r = wr * 32 + m * 16 + lr;
      int s = lq ^ ((r >> 1) & 3);
      af[m] = *(const bf16x8_t*)&As[cur][r * 32 + s * 8];
    }
#pragma unroll
    for (int n = 0; n < 4; n++) {
      int r = wc * 64 + n * 16 + lr;
      int s = lq ^ ((r >> 1) & 3);
      bfr[n] = *(const bf16x8_t*)&Bs[cur][r * 32 + s * 8];
    }
#pragma unroll
    for (int m = 0; m < 2; m++)
#pragma unroll
      for (int n = 0; n < 4; n++)
        acc[m][n] = __builtin_amdgcn_mfma_f32_16x16x32_bf16(af[m], bfr[n], acc[m][n], 0, 0, 0);
    if (pf) {
      if (tid < 256) {
        int r = tid >> 2, s = tid & 3;
        *(uint4*)&As[cur ^ 1][r * 32 + s * 8] = aReg;
      }
#pragma unroll
      for (int it = 0; it < 2; it++) {
        int lin = it * 512 + tid, r = lin >> 2, s = lin & 3;
        *(uint4*)&Bs[cur ^ 1][r * 32 + s * 8] = bReg[it];
      }
    }
    __syncthreads();
  }

  if constexpr (EPI == 0) {
#pragma unroll
    for (int m = 0; m < 2; m++)
#pragma unroll
      for (int n = 0; n < 4; n++)
#pragma unroll
        for (int j = 0; j < 4; j++) {
          int rl = wr * 32 + m * 16 + lq * 4 + j;
          int col = n0 + wc * 64 + n * 16 + lr;
          Out[(size_t)(m0 + rl) * strideO + col] = f2bf(acc[m][n][j]);
        }
  } else {
    float s1[2][4], s2[2][4];
#pragma unroll
    for (int m = 0; m < 2; m++)
#pragma unroll
      for (int j = 0; j < 4; j++) {
        float a = 0.f, b = 0.f;
#pragma unroll
        for (int n = 0; n < 4; n++) { float x = acc[m][n][j]; a += x; b += x * x; }
        s1[m][j] = a; s2[m][j] = b;
      }
#pragma unroll
    for (int mask = 1; mask < 16; mask <<= 1)
#pragma unroll
      for (int m = 0; m < 2; m++)
#pragma unroll
        for (int j = 0; j < 4; j++) {
          s1[m][j] += __shfl_xor(s1[m][j], mask, 64);
          s2[m][j] += __shfl_xor(s2[m][j], mask, 64);
        }
    if (lr == 0) {
#pragma unroll
      for (int m = 0; m < 2; m++)
#pragma unroll
        for (int j = 0; j < 4; j++) {
          int rl = wr * 32 + m * 16 + lq * 4 + j;
          redS[rl][wc] = s1[m][j];
          redQ[rl][wc] = s2[m][j];
        }
    }
    __syncthreads();
#pragma unroll
    for (int m = 0; m < 2; m++)
#pragma unroll
      for (int j = 0; j < 4; j++) {
        int rl = wr * 32 + m * 16 + lq * 4 + j;
        float ts = redS[rl][0] + redS[rl][1] + redS[rl][2] + redS[rl][3];
        float tq = redQ[rl][0] + redQ[rl][1] + redQ[rl][2] + redQ[rl][3];
        float mu = ts * (1.f / 256.f);
        float var = tq * (1.f / 256.f) - mu * mu;
        float rs = rsqrtf(var + LN_EPS);
#pragma unroll
        for (int n = 0; n < 4; n++) {
          int col = wc * 64 + n * 16 + lr;
          float v = (acc[m][n][j] - mu) * rs * gam[col] + bet[col];
          Out[(size_t)(m0 + rl) * strideO + col] = f2bf(v);
        }
      }
  }
}

// ---------------------------------------------------------------------------
// Attention: wave-per-token. qk precomputed (QKc bf16 [CHUNK][2048]).
// Phase5 reads Wv as f32 (no cvt) and tcl as float2.
// ---------------------------------------------------------------------------
__global__ __launch_bounds__(256) void attn_kernel(const unsigned short* __restrict__ QKc,
                                                   const float* __restrict__ target,
                                                   const float* __restrict__ wts,
                                                   const float* __restrict__ conf,
                                                   const float* __restrict__ Wv,
                                                   unsigned short* __restrict__ AO,
                                                   int t0) {
  __shared__ float scL[4][HH][PP];
  __shared__ float awL[4][HH][PP];
  __shared__ float tcl[4][HH][260];
  const int tid = threadIdx.x;
  const int w = tid >> 6, l = tid & 63;
  const int tl = blockIdx.x * 4 + w;
  const int t = t0 + tl;
  const float* trow = target + (size_t)t * PP * CC;

  float qk[HH][4];
  const unsigned short* qkrow = QKc + (size_t)tl * 2048;
#pragma unroll
  for (int h = 0; h < HH; h++) {
    ushort4 u = *(const ushort4*)&qkrow[h * 256 + 4 * l];
    qk[h][0] = bf2f(u.x); qk[h][1] = bf2f(u.y); qk[h][2] = bf2f(u.z); qk[h][3] = bf2f(u.w);
  }
  float4 tv[PP];
#pragma unroll
  for (int p = 0; p < PP; p++) tv[p] = *(const float4*)&trow[p * CC + 4 * l];

  const float rsD = 0.17677669529663687f;
#pragma unroll
  for (int p = 0; p < PP; p++) {
    float part[HH];
#pragma unroll
    for (int h = 0; h < HH; h++)
      part[h] = qk[h][0] * tv[p].x + qk[h][1] * tv[p].y + qk[h][2] * tv[p].z + qk[h][3] * tv[p].w;
#pragma unroll
    for (int m = 1; m < 64; m <<= 1)
#pragma unroll
      for (int h = 0; h < HH; h++) part[h] += __shfl_xor(part[h], m, 64);
    if (l == 0) {
      float wscale = wts[(size_t)t * PP + p] * rsD;
#pragma unroll
      for (int h = 0; h < HH; h++) scL[w][h][p] = part[h] * wscale;
    }
  }
  __syncthreads();

  {
    int p = l & 15;
    int h0 = l >> 4, h1 = h0 + 4;
    float cf = conf[(size_t)t * PP + p];
    float x0 = scL[w][h0][p], x1 = scL[w][h1][p];
    float m0 = x0, m1 = x1;
#pragma unroll
    for (int m = 1; m < 16; m <<= 1) {
      m0 = fmaxf(m0, __shfl_xor(m0, m, 64));
      m1 = fmaxf(m1, __shfl_xor(m1, m, 64));
    }
    float e0 = expf(x0 - m0), e1 = expf(x1 - m1);
    float s0 = e0, s1 = e1;
#pragma unroll
    for (int m = 1; m < 16; m <<= 1) {
      s0 += __shfl_xor(s0, m, 64);
      s1 += __shfl_xor(s1, m, 64);
    }
    awL[w][h0][p] = e0 / s0 * cf;
    awL[w][h1][p] = e1 / s1 * cf;
  }
  __syncthreads();

  float tc_[HH][4];
#pragma unroll
  for (int h = 0; h < HH; h++)
#pragma unroll
    for (int j = 0; j < 4; j++) tc_[h][j] = 0.f;
#pragma unroll
  for (int p = 0; p < PP; p++) {
#pragma unroll
    for (int h = 0; h < HH; h++) {
      float aw = awL[w][h][p];
      tc_[h][0] += aw * tv[p].x; tc_[h][1] += aw * tv[p].y;
      tc_[h][2] += aw * tv[p].z; tc_[h][3] += aw * tv[p].w;
    }
  }
#pragma unroll
  for (int h = 0; h < HH; h++)
    *(float4*)&tcl[w][h][4 * l] = make_float4(tc_[h][0], tc_[h][1], tc_[h][2], tc_[h][3]);
  __syncthreads();

  const int hh = l >> 3;
  float o[4] = {0.f, 0.f, 0.f, 0.f};
#pragma unroll 4
  for (int e = 0; e < CC; e += 2) {
    float2 tp = *(const float2*)&tcl[w][hh][e];
    float4 w0 = *(const float4*)&Wv[(size_t)e * CC + 4 * l];
    float4 w1 = *(const float4*)&Wv[(size_t)(e + 1) * CC + 4 * l];
    o[0] += tp.x * w0.x + tp.y * w1.x;
    o[1] += tp.x * w0.y + tp.y * w1.y;
    o[2] += tp.x * w0.z + tp.y * w1.z;
    o[3] += tp.x * w0.w + tp.y * w1.w;
  }
  *(ushort4*)&AO[(size_t)t * CC + 4 * l] = make_ushort4(f2bf(o[0]), f2bf(o[1]), f2bf(o[2]), f2bf(o[3]));
}

// ---------------------------------------------------------------------------
// Fused FFN v3: out = src + LN(gelu([SB||MSG] @ Wf1) @ Wf2)
// BM=64, 8 waves (4 row-groups x 2 col-groups). A-panel resident in LDS.
// BK=64 with double-buffered W1 + reg prefetch: 1 barrier / K-step.
// ---------------------------------------------------------------------------
__global__ __launch_bounds__(512) void ffn_mfma_kernel(
    const unsigned short* __restrict__ SB, const unsigned short* __restrict__ MSG,
    const unsigned short* __restrict__ W1t,  // [2048][512]
    const unsigned short* __restrict__ W2t,  // [256][2048]
    const float* __restrict__ g2, const float* __restrict__ b2,
    const float* __restrict__ src, float* __restrict__ out) {
  __shared__ __align__(16) unsigned short Afull[64 * 512];     // 64KB
  __shared__ __align__(16) unsigned short W1buf[2][128 * 64];  // 2x16KB
  __shared__ __align__(16) unsigned short hid[64 * 128];       // 16KB
  __shared__ __align__(16) unsigned short W2buf[256 * 64];     // 32KB
  __shared__ float redS[64][2], redQ[64][2];
  const int tid = threadIdx.x;
  const int wv = tid >> 6, l = tid & 63;
  const int wr = wv >> 1, wc = wv & 1;     // 4 row-groups x 2 col-groups
  const int lr = l & 15, lq = l >> 4;
  const int m0 = blockIdx.x * 64;

  // ---- stage resident A panel: rows m0..m0+63, k = [SB 256 || MSG 256] ----
#pragma unroll
  for (int it = 0; it < 8; it++) {
    int lin = it * 512 + tid, r = lin >> 6, s = lin & 63;
    const unsigned short* gp = (s < 32) ? &SB[(size_t)(m0 + r) * CC + s * 8]
                                        : &MSG[(size_t)(m0 + r) * CC + s * 8 - 256];
    uint4 v = *(const uint4*)gp;
    *(uint4*)&Afull[r * 512 + ((s ^ (r & 7)) << 3)] = v;
  }
  // ---- stage first W1 panel into buf0 ----
  uint4 w1r[2];
#pragma unroll
  for (int it = 0; it < 2; it++) {
    int lin = it * 512 + tid, r = lin >> 3, s = lin & 7;
    w1r[it] = *(const uint4*)&W1t[(size_t)r * 512 + s * 8];
    *(uint4*)&W1buf[0][r * 64 + ((s ^ (r & 7)) << 3)] = w1r[it];
  }
  __syncthreads();

  f32x4_t acc[8];
#pragma unroll
  for (int n = 0; n < 8; n++) acc[n] = (f32x4_t){0.f, 0.f, 0.f, 0.f};

  for (int hc = 0; hc < 16; hc++) {
    f32x4_t acc2[4];
#pragma unroll
    for (int n = 0; n < 4; n++) acc2[n] = (f32x4_t){0.f, 0.f, 0.f, 0.f};

    // ---- GEMM1: h_chunk[64,128] = A[64,512] @ W1t[hc*128..+128, :]^T ----
    for (int ks = 0; ks < 8; ks++) {
      int p = hc * 8 + ks, cur = p & 1;
      bool pf = (p + 1) < 128;
      if (pf) {
        int nhc = (p + 1) >> 3, nks = (p + 1) & 7;
#pragma unroll
        for (int it = 0; it < 2; it++) {
          int lin = it * 512 + tid, r = lin >> 3, s = lin & 7;
          w1r[it] = *(const uint4*)&W1t[(size_t)(nhc * 128 + r) * 512 + nks * 64 + s * 8];
        }
      }
      bf16x8_t af[2], bw[4][2];
#pragma unroll
      for (int kk = 0; kk < 2; kk++) {
        int r = wr * 16 + lr;
        int slot = ks * 8 + kk * 4 + lq;
        af[kk] = *(const bf16x8_t*)&Afull[r * 512 + ((slot ^ (r & 7)) << 3)];
      }
#pragma unroll
      for (int n = 0; n < 4; n++)
#pragma unroll
        for (int kk = 0; kk < 2; kk++) {
          int r = wc * 64 + n * 16 + lr;
          int slot = kk * 4 + lq;
          bw[n][kk] = *(const bf16x8_t*)&W1buf[cur][r * 64 + ((slot ^ (r & 7)) << 3)];
        }
#pragma unroll
      for (int n = 0; n < 4; n++)
#pragma unroll
        for (int kk = 0; kk < 2; kk++)
          acc2[n] = __builtin_amdgcn_mfma_f32_16x16x32_bf16(af[kk], bw[n][kk], acc2[n], 0, 0, 0);
      if (pf) {
#pragma unroll
        for (int it = 0; it < 2; it++) {
          int lin = it * 512 + tid, r = lin >> 3, s = lin & 7;
          *(uint4*)&W1buf[cur ^ 1][r * 64 + ((s ^ (r & 7)) << 3)] = w1r[it];
        }
      }
      __syncthreads();
    }

    // ---- issue W2 half-0 loads (hide under gelu) ----
    uint4 w2r[4];
#pragma unroll
    for (int it = 0; it < 4; it++) {
      int lin = it * 512 + tid, r = lin >> 3, s = lin & 7;
      w2r[it] = *(const uint4*)&W2t[(size_t)r * 2048 + hc * 128 + s * 8];
    }
    // ---- gelu -> hid (swizzled) ----
#pragma unroll
    for (int n = 0; n < 4; n++)
#pragma unroll
      for (int j = 0; j < 4; j++) {
        int row = wr * 16 + lq * 4 + j;
        int col = wc * 64 + n * 16 + lr;
        float x = acc2[n][j];
        float gl = 0.5f * x * (1.0f + erff(x * 0.70710678118654752f));
        hid[(row * 128 + col) ^ ((row & 7) << 3)] = f2bf(gl);
      }
    // ---- write W2 half-0 ----
#pragma unroll
    for (int it = 0; it < 4; it++) {
      int lin = it * 512 + tid, r = lin >> 3, s = lin & 7;
      *(uint4*)&W2buf[r * 64 + ((s ^ (r & 7)) << 3)] = w2r[it];
    }
    __syncthreads();

    // ---- issue W2 half-1 loads ----
#pragma unroll
    for (int it = 0; it < 4; it++) {
      int lin = it * 512 + tid, r = lin >> 3, s = lin & 7;
      w2r[it] = *(const uint4*)&W2t[(size_t)r * 2048 + hc * 128 + 64 + s * 8];
    }
    // ---- GEMM2 half-0 ----
#pragma unroll
    for (int h2 = 0; h2 < 2; h2++) {
      bf16x8_t ah[2];
#pragma unroll
      for (int kk = 0; kk < 2; kk++) {
        int row = wr * 16 + lr;
        int slot = h2 * 8 + kk * 4 + lq;
        ah[kk] = *(const bf16x8_t*)&hid[row * 128 + ((slot ^ (row & 7)) << 3)];
      }
#pragma unroll
      for (int n = 0; n < 8; n++) {
        bf16x8_t b2f[2];
#pragma unroll
        for (int kk = 0; kk < 2; kk++) {
          int r = wc * 128 + n * 16 + lr;
          int slot = kk * 4 + lq;
          b2f[kk] = *(const bf16x8_t*)&W2buf[r * 64 + ((slot ^ (r & 7)) << 3)];
        }
#pragma unroll
        for (int kk = 0; kk < 2; kk++)
          acc[n] = __builtin_amdgcn_mfma_f32_16x16x32_bf16(ah[kk], b2f[kk], acc[n], 0, 0, 0);
      }
      if (h2 == 0) {
        __syncthreads();
        // write W2 half-1
#pragma unroll
        for (int it = 0; it < 4; it++) {
          int lin = it * 512 + tid, r = lin >> 3, s = lin & 7;
          *(uint4*)&W2buf[r * 64 + ((s ^ (r & 7)) << 3)] = w2r[it];
        }
        __syncthreads();
      }
    }
    // no barrier needed here: next GEMM1 touches Afull/W1buf only; hid & W2buf
    // rewrites are protected by the 8 ks-barriers of the next chunk.
  }

  // ---- LN + residual epilogue ----
  float s1[4], s2[4];
#pragma unroll
  for (int j = 0; j < 4; j++) {
    float a = 0.f, b = 0.f;
#pragma unroll
    for (int n = 0; n < 8; n++) { float x = acc[n][j]; a += x; b += x * x; }
    s1[j] = a; s2[j] = b;
  }
#pragma unroll
  for (int mask = 1; mask < 16; mask <<= 1)
#pragma unroll
    for (int j = 0; j < 4; j++) {
      s1[j] += __shfl_xor(s1[j], mask, 64);
      s2[j] += __shfl_xor(s2[j], mask, 64);
    }
  __syncthreads();   // guard redS reuse vs last GEMM2 reads
  if (lr == 0) {
#pragma unroll
    for (int j = 0; j < 4; j++) {
      int row = wr * 16 + lq * 4 + j;
      redS[row][wc] = s1[j];
      redQ[row][wc] = s2[j];
    }
  }
  __syncthreads();
#pragma unroll
  for (int j = 0; j < 4; j++) {
    int row = wr * 16 + lq * 4 + j;
    float ts = redS[row][0] + redS[row][1];
    float tq = redQ[row][0] + redQ[row][1];
    float mu = ts * (1.f / 256.f);
    float var = tq * (1.f / 256.f) - mu * mu;
    float rs = rsqrtf(var + LN_EPS);
    size_t rowg = (size_t)(m0 + row);
#pragma unroll
    for (int n = 0; n < 8; n++) {
      int col = wc * 128 + n * 16 + lr;
      float v = src[rowg * CC + col] + (acc[n][j] - mu) * rs * g2[col] + b2[col];
      out[rowg * CC + col] = v;
    }
  }
}

extern "C" void kernel_launch(void* const* d_in, const int* in_sizes, int n_in,
                              void* d_out, int out_size, void* d_ws, size_t ws_size,
                              hipStream_t stream) {
  const float* source = (const float*)d_in[0];
  const float* target = (const float*)d_in[1];
  const float* weights = (const float*)d_in[2];
  const float* conf   = (const float*)d_in[3];
  const float* Wq = (const float*)d_in[4];
  const float* Wk = (const float*)d_in[5];
  const float* Wv = (const float*)d_in[6];
  const float* Wm = (const float*)d_in[7];
  const float* g1 = (const float*)d_in[8];
  const float* b1 = (const float*)d_in[9];
  const float* Wf1 = (const float*)d_in[10];
  const float* Wf2 = (const float*)d_in[11];
  const float* g2 = (const float*)d_in[12];
  const float* b2 = (const float*)d_in[13];
  float* out = (float*)d_out;

  unsigned short* SB   = (unsigned short*)d_ws;                 // [16384][256]
  unsigned short* MSGb = SB + (size_t)T_TOK * CC;               // [16384][256]
  unsigned short* QKc  = MSGb + (size_t)T_TOK * CC;             // [2048][2048]
  unsigned short* Mt   = QKc + (size_t)CHUNK * 2048;            // [2048][256]
  unsigned short* WMt  = Mt + (size_t)2048 * 256;               // [256][256]
  unsigned short* WF1t = WMt + (size_t)256 * 256;               // [2048][512]
  unsigned short* WF2t = WF1t + (size_t)2048 * 512;             // [256][2048]
  unsigned short* AObf = (unsigned short*)d_out;                // parked in d_out

  // prep
  cvt_bf16_kernel<<<T_TOK * CC / 1024, 256, 0, stream>>>(source, SB);
  transpose_cvt_kernel<<<dim3(4, 4), 256, 0, stream>>>(Wm, WMt, 256, 256);
  transpose_cvt_kernel<<<dim3(8, 32), 256, 0, stream>>>(Wf1, WF1t, 512, 2048);
  transpose_cvt_kernel<<<dim3(32, 4), 256, 0, stream>>>(Wf2, WF2t, 2048, 256);
  precM_kernel<<<2048, 256, 0, stream>>>(Wq, Wk, Mt);

  // attention pipeline, chunked
  for (int c = 0; c < T_TOK / CHUNK; c++) {
    int t0 = c * CHUNK;
    mfma_gemm_kernel<0><<<dim3(CHUNK / 64, 8), 512, 0, stream>>>(
        SB + (size_t)t0 * CC, Mt, QKc, nullptr, nullptr, 256, 2048);
    attn_kernel<<<CHUNK / 4, 256, 0, stream>>>(QKc, target, weights, conf, Wv, AObf, t0);
  }
  // message = LN(AO @ Wm)
  mfma_gemm_kernel<1><<<dim3(T_TOK / 64, 1), 512, 0, stream>>>(
      AObf, WMt, MSGb, g1, b1, 256, 256);
  // out = src + LN(gelu([SB||MSG] @ Wf1) @ Wf2)
  ffn_mfma_kernel<<<T_TOK / 64, 512, 0, stream>>>(SB, MSGb, WF1t, WF2t, g2, b2, source, out);
}

// Round 4
// 564.848 us; speedup vs baseline: 1.1792x; 1.1792x over previous
//
#include <hip/hip_runtime.h>
#include <hip/hip_bf16.h>
#include <math.h>

#define T_TOK 16384
#define CC 256
#define PP 16
#define HH 8
#define DD 32
#define LN_EPS 1e-5f
#define CHUNK 2048

typedef __attribute__((ext_vector_type(8))) short bf16x8_t;
typedef __attribute__((ext_vector_type(4))) float f32x4_t;

__device__ __forceinline__ unsigned short f2bf(float x) {
  __hip_bfloat16 h = __float2bfloat16(x);
  return *reinterpret_cast<unsigned short*>(&h);
}
__device__ __forceinline__ float bf2f(unsigned short u) {
  union { unsigned int i; float f; } v; v.i = ((unsigned int)u) << 16; return v.f;
}

// ---------------------------------------------------------------------------
// Prep kernels
// ---------------------------------------------------------------------------
__global__ __launch_bounds__(256) void cvt_bf16_kernel(const float* __restrict__ src,
                                                       unsigned short* __restrict__ dst) {
  int i = (blockIdx.x * 256 + threadIdx.x) * 4;
  float4 v = *(const float4*)&src[i];
  ushort4 o = make_ushort4(f2bf(v.x), f2bf(v.y), f2bf(v.z), f2bf(v.w));
  *(ushort4*)&dst[i] = o;
}

__global__ __launch_bounds__(256) void transpose_cvt_kernel(const float* __restrict__ src,
                                                            unsigned short* __restrict__ dst,
                                                            int K, int N) {
  __shared__ float tile[64][65];
  int k0 = blockIdx.x * 64, n0 = blockIdx.y * 64;
  int tid = threadIdx.x;
#pragma unroll
  for (int i = 0; i < 16; i++) {
    int lin = i * 256 + tid, r = lin >> 6, c = lin & 63;
    tile[r][c] = src[(size_t)(k0 + r) * N + n0 + c];
  }
  __syncthreads();
#pragma unroll
  for (int i = 0; i < 16; i++) {
    int lin = i * 256 + tid, n = lin >> 6, k = lin & 63;
    dst[(size_t)(n0 + n) * K + k0 + k] = f2bf(tile[k][n]);
  }
}

// Mt[(h*256+e)][c] = bf16( sum_d Wq[c][h*32+d] * Wk[e][h*32+d] )
__global__ __launch_bounds__(256) void precM_kernel(const float* __restrict__ Wq,
                                                    const float* __restrict__ Wk,
                                                    unsigned short* __restrict__ Mt) {
  int n = blockIdx.x;
  int h = n >> 8, e = n & 255;
  int c = threadIdx.x;
  const float* wkrow = Wk + (size_t)e * CC + h * DD;
  const float* wqrow = Wq + (size_t)c * CC + h * DD;
  float s = 0.f;
#pragma unroll
  for (int d = 0; d < DD; d++) s += wqrow[d] * wkrow[d];
  Mt[(size_t)n * CC + c] = f2bf(s);
}

// ---------------------------------------------------------------------------
// MFMA GEMM: Out[M,*] = A[M,K] @ Bt^T  (Bt [N][K] bf16), BM=64 BN=256 BK=32.
// EPI 0: bf16 store. EPI 1: LN(g,b) -> bf16.
// ---------------------------------------------------------------------------
template<int EPI>
__global__ __launch_bounds__(512) void mfma_gemm_kernel(
    const unsigned short* __restrict__ A, const unsigned short* __restrict__ Bt,
    unsigned short* __restrict__ Out, const float* __restrict__ gam,
    const float* __restrict__ bet, int K, int strideO) {
  __shared__ __align__(16) unsigned short As[2][64 * 32];
  __shared__ __align__(16) unsigned short Bs[2][256 * 32];
  __shared__ float redS[64][5], redQ[64][5];
  const int tid = threadIdx.x;
  const int wv = tid >> 6, l = tid & 63;
  const int wr = wv >> 2, wc = wv & 3;
  const int lr = l & 15, lq = l >> 4;
  const int m0 = blockIdx.x * 64;
  const int n0 = blockIdx.y * 256;
  const int nsteps = K >> 5;

  f32x4_t acc[2][4];
#pragma unroll
  for (int m = 0; m < 2; m++)
#pragma unroll
    for (int n = 0; n < 4; n++) acc[m][n] = (f32x4_t){0.f, 0.f, 0.f, 0.f};

  uint4 aReg; uint4 bReg[2];
  if (tid < 256) {
    int r = tid >> 2, s = tid & 3, q = s ^ ((r >> 1) & 3);
    aReg = *(const uint4*)&A[(size_t)(m0 + r) * K + q * 8];
    *(uint4*)&As[0][r * 32 + s * 8] = aReg;
  }
#pragma unroll
  for (int it = 0; it < 2; it++) {
    int lin = it * 512 + tid, r = lin >> 2, s = lin & 3, q = s ^ ((r >> 1) & 3);
    bReg[it] = *(const uint4*)&Bt[(size_t)(n0 + r) * K + q * 8];
    *(uint4*)&Bs[0][r * 32 + s * 8] = bReg[it];
  }
  __syncthreads();

  for (int st = 0; st < nsteps; st++) {
    int cur = st & 1;
    bool pf = (st + 1) < nsteps;
    if (pf) {
      int kn = (st + 1) * 32;
      if (tid < 256) {
        int r = tid >> 2, s = tid & 3, q = s ^ ((r >> 1) & 3);
        aReg = *(const uint4*)&A[(size_t)(m0 + r) * K + kn + q * 8];
      }
#pragma unroll
      for (int it = 0; it < 2; it++) {
        int lin = it * 512 + tid, r = lin >> 2, s = lin & 3, q = s ^ ((r >> 1) & 3);
        bReg[it] = *(const uint4*)&Bt[(size_t)(n0 + r) * K + kn + q * 8];
      }
    }
    bf16x8_t af[2], bfr[4];
#pragma unroll
    for (int m = 0; m < 2; m++) {
      int r = wr * 32 + m * 16 + lr;
      int s = lq ^ ((r >> 1) & 3);
      af[m] = *(const bf16x8_t*)&As[cur][r * 32 + s * 8];
    }
#pragma unroll
    for (int n = 0; n < 4; n++) {
      int r = wc * 64 + n * 16 + lr;
      int s = lq ^ ((r >> 1) & 3);
      bfr[n] = *(const bf16x8_t*)&Bs[cur][r * 32 + s * 8];
    }
#pragma unroll
    for (int m = 0; m < 2; m++)
#pragma unroll
      for (int n = 0; n < 4; n++)
        acc[m][n] = __builtin_amdgcn_mfma_f32_16x16x32_bf16(af[m], bfr[n], acc[m][n], 0, 0, 0);
    if (pf) {
      if (tid < 256) {
        int r = tid >> 2, s = tid & 3;
        *(uint4*)&As[cur ^ 1][r * 32 + s * 8] = aReg;
      }
#pragma unroll
      for (int it = 0; it < 2; it++) {
        int lin = it * 512 + tid, r = lin >> 2, s = lin & 3;
        *(uint4*)&Bs[cur ^ 1][r * 32 + s * 8] = bReg[it];
      }
    }
    __syncthreads();
  }

  if constexpr (EPI == 0) {
#pragma unroll
    for (int m = 0; m < 2; m++)
#pragma unroll
      for (int n = 0; n < 4; n++)
#pragma unroll
        for (int j = 0; j < 4; j++) {
          int rl = wr * 32 + m * 16 + lq * 4 + j;
          int col = n0 + wc * 64 + n * 16 + lr;
          Out[(size_t)(m0 + rl) * strideO + col] = f2bf(acc[m][n][j]);
        }
  } else {
    float s1[2][4], s2[2][4];
#pragma unroll
    for (int m = 0; m < 2; m++)
#pragma unroll
      for (int j = 0; j < 4; j++) {
        float a = 0.f, b = 0.f;
#pragma unroll
        for (int n = 0; n < 4; n++) { float x = acc[m][n][j]; a += x; b += x * x; }
        s1[m][j] = a; s2[m][j] = b;
      }
#pragma unroll
    for (int mask = 1; mask < 16; mask <<= 1)
#pragma unroll
      for (int m = 0; m < 2; m++)
#pragma unroll
        for (int j = 0; j < 4; j++) {
          s1[m][j] += __shfl_xor(s1[m][j], mask, 64);
          s2[m][j] += __shfl_xor(s2[m][j], mask, 64);
        }
    if (lr == 0) {
#pragma unroll
      for (int m = 0; m < 2; m++)
#pragma unroll
        for (int j = 0; j < 4; j++) {
          int rl = wr * 32 + m * 16 + lq * 4 + j;
          redS[rl][wc] = s1[m][j];
          redQ[rl][wc] = s2[m][j];
        }
    }
    __syncthreads();
#pragma unroll
    for (int m = 0; m < 2; m++)
#pragma unroll
      for (int j = 0; j < 4; j++) {
        int rl = wr * 32 + m * 16 + lq * 4 + j;
        float ts = redS[rl][0] + redS[rl][1] + redS[rl][2] + redS[rl][3];
        float tq = redQ[rl][0] + redQ[rl][1] + redQ[rl][2] + redQ[rl][3];
        float mu = ts * (1.f / 256.f);
        float var = tq * (1.f / 256.f) - mu * mu;
        float rs = rsqrtf(var + LN_EPS);
#pragma unroll
        for (int n = 0; n < 4; n++) {
          int col = wc * 64 + n * 16 + lr;
          float v = (acc[m][n][j] - mu) * rs * gam[col] + bet[col];
          Out[(size_t)(m0 + rl) * strideO + col] = f2bf(v);
        }
      }
  }
}

// ---------------------------------------------------------------------------
// Attention: 4 waves = 4 tokens per block. Phases 1-4 per-wave; phase 5
// (Wv projection) block-cooperative: e-range split across waves, 4 tokens
// batched per Wv read, partials reduced through LDS.
// ---------------------------------------------------------------------------
__global__ __launch_bounds__(256) void attn_kernel(const unsigned short* __restrict__ QKc,
                                                   const float* __restrict__ target,
                                                   const float* __restrict__ wts,
                                                   const float* __restrict__ conf,
                                                   const float* __restrict__ Wv,
                                                   unsigned short* __restrict__ AO,
                                                   int t0) {
  __shared__ float scL[4][HH][PP];
  __shared__ float awL[4][HH][PP];
  __shared__ float tcl[4][HH][260];
  __shared__ float prS[4][4][256];   // [wave][tok][col]
  const int tid = threadIdx.x;
  const int w = tid >> 6, l = tid & 63;
  const int tl = blockIdx.x * 4 + w;
  const int t = t0 + tl;
  const float* trow = target + (size_t)t * PP * CC;

  float qk[HH][4];
  const unsigned short* qkrow = QKc + (size_t)tl * 2048;
#pragma unroll
  for (int h = 0; h < HH; h++) {
    ushort4 u = *(const ushort4*)&qkrow[h * 256 + 4 * l];
    qk[h][0] = bf2f(u.x); qk[h][1] = bf2f(u.y); qk[h][2] = bf2f(u.z); qk[h][3] = bf2f(u.w);
  }
  float4 tv[PP];
#pragma unroll
  for (int p = 0; p < PP; p++) tv[p] = *(const float4*)&trow[p * CC + 4 * l];

  const float rsD = 0.17677669529663687f;
#pragma unroll
  for (int p = 0; p < PP; p++) {
    float part[HH];
#pragma unroll
    for (int h = 0; h < HH; h++)
      part[h] = qk[h][0] * tv[p].x + qk[h][1] * tv[p].y + qk[h][2] * tv[p].z + qk[h][3] * tv[p].w;
#pragma unroll
    for (int m = 1; m < 64; m <<= 1)
#pragma unroll
      for (int h = 0; h < HH; h++) part[h] += __shfl_xor(part[h], m, 64);
    if (l == 0) {
      float wscale = wts[(size_t)t * PP + p] * rsD;
#pragma unroll
      for (int h = 0; h < HH; h++) scL[w][h][p] = part[h] * wscale;
    }
  }
  __syncthreads();

  {
    int p = l & 15;
    int h0 = l >> 4, h1 = h0 + 4;
    float cf = conf[(size_t)t * PP + p];
    float x0 = scL[w][h0][p], x1 = scL[w][h1][p];
    float m0 = x0, m1 = x1;
#pragma unroll
    for (int m = 1; m < 16; m <<= 1) {
      m0 = fmaxf(m0, __shfl_xor(m0, m, 64));
      m1 = fmaxf(m1, __shfl_xor(m1, m, 64));
    }
    float e0 = expf(x0 - m0), e1 = expf(x1 - m1);
    float s0 = e0, s1 = e1;
#pragma unroll
    for (int m = 1; m < 16; m <<= 1) {
      s0 += __shfl_xor(s0, m, 64);
      s1 += __shfl_xor(s1, m, 64);
    }
    awL[w][h0][p] = e0 / s0 * cf;
    awL[w][h1][p] = e1 / s1 * cf;
  }
  __syncthreads();

  float tc_[HH][4];
#pragma unroll
  for (int h = 0; h < HH; h++)
#pragma unroll
    for (int j = 0; j < 4; j++) tc_[h][j] = 0.f;
#pragma unroll
  for (int p = 0; p < PP; p++) {
#pragma unroll
    for (int h = 0; h < HH; h++) {
      float aw = awL[w][h][p];
      tc_[h][0] += aw * tv[p].x; tc_[h][1] += aw * tv[p].y;
      tc_[h][2] += aw * tv[p].z; tc_[h][3] += aw * tv[p].w;
    }
  }
#pragma unroll
  for (int h = 0; h < HH; h++)
    *(float4*)&tcl[w][h][4 * l] = make_float4(tc_[h][0], tc_[h][1], tc_[h][2], tc_[h][3]);
  __syncthreads();

  // ---- phase 5: e-split across waves, 4 tokens batched ----
  const int hh = l >> 3;
  float po[4][4];
#pragma unroll
  for (int tok = 0; tok < 4; tok++)
#pragma unroll
    for (int j = 0; j < 4; j++) po[tok][j] = 0.f;
  const float* wvb = Wv + (size_t)(w * 64) * CC + 4 * l;
#pragma unroll 8
  for (int e = 0; e < 64; e += 2) {
    float4 w0 = *(const float4*)&wvb[(size_t)e * CC];
    float4 w1 = *(const float4*)&wvb[(size_t)(e + 1) * CC];
    int eg = w * 64 + e;
#pragma unroll
    for (int tok = 0; tok < 4; tok++) {
      float2 tp = *(const float2*)&tcl[tok][hh][eg];
      po[tok][0] += tp.x * w0.x + tp.y * w1.x;
      po[tok][1] += tp.x * w0.y + tp.y * w1.y;
      po[tok][2] += tp.x * w0.z + tp.y * w1.z;
      po[tok][3] += tp.x * w0.w + tp.y * w1.w;
    }
  }
#pragma unroll
  for (int tok = 0; tok < 4; tok++)
    *(float4*)&prS[w][tok][4 * l] = make_float4(po[tok][0], po[tok][1], po[tok][2], po[tok][3]);
  __syncthreads();
  {
    int tok = tid >> 6;
    int cb = (tid & 63) * 4;
    float4 a0 = *(const float4*)&prS[0][tok][cb];
    float4 a1 = *(const float4*)&prS[1][tok][cb];
    float4 a2 = *(const float4*)&prS[2][tok][cb];
    float4 a3 = *(const float4*)&prS[3][tok][cb];
    float ox = a0.x + a1.x + a2.x + a3.x;
    float oy = a0.y + a1.y + a2.y + a3.y;
    float oz = a0.z + a1.z + a2.z + a3.z;
    float ow = a0.w + a1.w + a2.w + a3.w;
    int tg = t0 + blockIdx.x * 4 + tok;
    *(ushort4*)&AO[(size_t)tg * CC + cb] = make_ushort4(f2bf(ox), f2bf(oy), f2bf(oz), f2bf(ow));
  }
}

// ---------------------------------------------------------------------------
// FFN GEMM1 (unfused): hid[16384,2048] = gelu([SB||MSG] @ W1t^T), bf16 out.
// BM=128, BN=128, 256 thr, 4 waves (2x2), wave tile 64x64 (4x4 frags).
// ---------------------------------------------------------------------------
__global__ __launch_bounds__(256) void gemm1_kernel(
    const unsigned short* __restrict__ SB, const unsigned short* __restrict__ MSG,
    const unsigned short* __restrict__ W1t, unsigned short* __restrict__ hid) {
  __shared__ __align__(16) unsigned short As[2][128 * 32];
  __shared__ __align__(16) unsigned short Bs[2][128 * 32];
  const int tid = threadIdx.x;
  const int wv = tid >> 6, l = tid & 63;
  const int wr = wv >> 1, wc = wv & 1;
  const int lr = l & 15, lq = l >> 4;
  const int m0 = blockIdx.x * 128;
  const int n0 = blockIdx.y * 128;

  f32x4_t acc[4][4];
#pragma unroll
  for (int m = 0; m < 4; m++)
#pragma unroll
    for (int n = 0; n < 4; n++) acc[m][n] = (f32x4_t){0.f, 0.f, 0.f, 0.f};

  uint4 aR[2], bR[2];
  // stage step 0
#pragma unroll
  for (int it = 0; it < 2; it++) {
    int lin = it * 256 + tid, r = lin >> 2, s = lin & 3, q = s ^ ((r >> 1) & 3);
    int ka = q * 8;  // k0 = 0 < 256 -> SB
    aR[it] = *(const uint4*)&SB[(size_t)(m0 + r) * CC + ka];
    *(uint4*)&As[0][r * 32 + s * 8] = aR[it];
    bR[it] = *(const uint4*)&W1t[(size_t)(n0 + r) * 512 + q * 8];
    *(uint4*)&Bs[0][r * 32 + s * 8] = bR[it];
  }
  __syncthreads();

  for (int st = 0; st < 16; st++) {
    int cur = st & 1;
    bool pf = st < 15;
    if (pf) {
      int kn = (st + 1) * 32;
#pragma unroll
      for (int it = 0; it < 2; it++) {
        int lin = it * 256 + tid, r = lin >> 2, s = lin & 3, q = s ^ ((r >> 1) & 3);
        int ka = kn + q * 8;
        const unsigned short* ap = (ka < 256) ? &SB[(size_t)(m0 + r) * CC + ka]
                                              : &MSG[(size_t)(m0 + r) * CC + ka - 256];
        aR[it] = *(const uint4*)ap;
        bR[it] = *(const uint4*)&W1t[(size_t)(n0 + r) * 512 + kn + q * 8];
      }
    }
    bf16x8_t af[4], bf[4];
#pragma unroll
    for (int m = 0; m < 4; m++) {
      int r = wr * 64 + m * 16 + lr;
      int s = lq ^ ((r >> 1) & 3);
      af[m] = *(const bf16x8_t*)&As[cur][r * 32 + s * 8];
    }
#pragma unroll
    for (int n = 0; n < 4; n++) {
      int r = wc * 64 + n * 16 + lr;
      int s = lq ^ ((r >> 1) & 3);
      bf[n] = *(const bf16x8_t*)&Bs[cur][r * 32 + s * 8];
    }
#pragma unroll
    for (int m = 0; m < 4; m++)
#pragma unroll
      for (int n = 0; n < 4; n++)
        acc[m][n] = __builtin_amdgcn_mfma_f32_16x16x32_bf16(af[m], bf[n], acc[m][n], 0, 0, 0);
    if (pf) {
#pragma unroll
      for (int it = 0; it < 2; it++) {
        int lin = it * 256 + tid, r = lin >> 2, s = lin & 3;
        *(uint4*)&As[cur ^ 1][r * 32 + s * 8] = aR[it];
        *(uint4*)&Bs[cur ^ 1][r * 32 + s * 8] = bR[it];
      }
    }
    __syncthreads();
  }

  // gelu epilogue -> bf16 hid
#pragma unroll
  for (int m = 0; m < 4; m++)
#pragma unroll
    for (int n = 0; n < 4; n++)
#pragma unroll
      for (int j = 0; j < 4; j++) {
        int row = m0 + wr * 64 + m * 16 + lq * 4 + j;
        int col = n0 + wc * 64 + n * 16 + lr;
        float x = acc[m][n][j];
        float gl = 0.5f * x * (1.0f + erff(x * 0.70710678118654752f));
        hid[(size_t)row * 2048 + col] = f2bf(gl);
      }
}

// ---------------------------------------------------------------------------
// FFN GEMM2 (unfused): raw[16384,256] = hid @ W2t^T (f32 raw to d_out).
// BM=64, BN=128, 256 thr, 4 waves (2x2), wave tile 32x64 (2x4 frags).
// ---------------------------------------------------------------------------
__global__ __launch_bounds__(256) void gemm2_kernel(
    const unsigned short* __restrict__ hid, const unsigned short* __restrict__ W2t,
    float* __restrict__ outRaw) {
  __shared__ __align__(16) unsigned short As[2][64 * 32];
  __shared__ __align__(16) unsigned short Bs[2][128 * 32];
  const int tid = threadIdx.x;
  const int wv = tid >> 6, l = tid & 63;
  const int wr = wv >> 1, wc = wv & 1;
  const int lr = l & 15, lq = l >> 4;
  const int m0 = blockIdx.x * 64;
  const int n0 = blockIdx.y * 128;

  f32x4_t acc[2][4];
#pragma unroll
  for (int m = 0; m < 2; m++)
#pragma unroll
    for (int n = 0; n < 4; n++) acc[m][n] = (f32x4_t){0.f, 0.f, 0.f, 0.f};

  uint4 aR, bR[2];
  {
    int r = tid >> 2, s = tid & 3, q = s ^ ((r >> 1) & 3);
    aR = *(const uint4*)&hid[(size_t)(m0 + r) * 2048 + q * 8];
    *(uint4*)&As[0][r * 32 + s * 8] = aR;
  }
#pragma unroll
  for (int it = 0; it < 2; it++) {
    int lin = it * 256 + tid, r = lin >> 2, s = lin & 3, q = s ^ ((r >> 1) & 3);
    bR[it] = *(const uint4*)&W2t[(size_t)(n0 + r) * 2048 + q * 8];
    *(uint4*)&Bs[0][r * 32 + s * 8] = bR[it];
  }
  __syncthreads();

  for (int st = 0; st < 64; st++) {
    int cur = st & 1;
    bool pf = st < 63;
    if (pf) {
      int kn = (st + 1) * 32;
      {
        int r = tid >> 2, s = tid & 3, q = s ^ ((r >> 1) & 3);
        aR = *(const uint4*)&hid[(size_t)(m0 + r) * 2048 + kn + q * 8];
      }
#pragma unroll
      for (int it = 0; it < 2; it++) {
        int lin = it * 256 + tid, r = lin >> 2, s = lin & 3, q = s ^ ((r >> 1) & 3);
        bR[it] = *(const uint4*)&W2t[(size_t)(n0 + r) * 2048 + kn + q * 8];
      }
    }
    bf16x8_t af[2], bf[4];
#pragma unroll
    for (int m = 0; m < 2; m++) {
      int r = wr * 32 + m * 16 + lr;
      int s = lq ^ ((r >> 1) & 3);
      af[m] = *(const bf16x8_t*)&As[cur][r * 32 + s * 8];
    }
#pragma unroll
    for (int n = 0; n < 4; n++) {
      int r = wc * 64 + n * 16 + lr;
      int s = lq ^ ((r >> 1) & 3);
      bf[n] = *(const bf16x8_t*)&Bs[cur][r * 32 + s * 8];
    }
#pragma unroll
    for (int m = 0; m < 2; m++)
#pragma unroll
      for (int n = 0; n < 4; n++)
        acc[m][n] = __builtin_amdgcn_mfma_f32_16x16x32_bf16(af[m], bf[n], acc[m][n], 0, 0, 0);
    if (pf) {
      {
        int r = tid >> 2, s = tid & 3;
        *(uint4*)&As[cur ^ 1][r * 32 + s * 8] = aR;
      }
#pragma unroll
      for (int it = 0; it < 2; it++) {
        int lin = it * 256 + tid, r = lin >> 2, s = lin & 3;
        *(uint4*)&Bs[cur ^ 1][r * 32 + s * 8] = bR[it];
      }
    }
    __syncthreads();
  }

#pragma unroll
  for (int m = 0; m < 2; m++)
#pragma unroll
    for (int n = 0; n < 4; n++)
#pragma unroll
      for (int j = 0; j < 4; j++) {
        int row = m0 + wr * 32 + m * 16 + lq * 4 + j;
        int col = n0 + wc * 64 + n * 16 + lr;
        outRaw[(size_t)row * CC + col] = acc[m][n][j];
      }
}

// LN + residual over raw f32 rows, in place on d_out.
__global__ __launch_bounds__(256) void ln_res_kernel(float* __restrict__ y,
                                                     const float* __restrict__ src,
                                                     const float* __restrict__ g2,
                                                     const float* __restrict__ b2) {
  const int l = threadIdx.x & 63;
  const int row = blockIdx.x * 4 + (threadIdx.x >> 6);
  size_t base = (size_t)row * CC + 4 * l;
  float4 v = *(const float4*)&y[base];
  float s1 = v.x + v.y + v.z + v.w;
  float s2 = v.x * v.x + v.y * v.y + v.z * v.z + v.w * v.w;
#pragma unroll
  for (int m = 1; m < 64; m <<= 1) {
    s1 += __shfl_xor(s1, m, 64);
    s2 += __shfl_xor(s2, m, 64);
  }
  float mu = s1 * (1.f / 256.f);
  float var = s2 * (1.f / 256.f) - mu * mu;
  float rs = rsqrtf(var + LN_EPS);
  float4 g = *(const float4*)&g2[4 * l];
  float4 b = *(const float4*)&b2[4 * l];
  float4 s = *(const float4*)&src[base];
  float4 o;
  o.x = s.x + (v.x - mu) * rs * g.x + b.x;
  o.y = s.y + (v.y - mu) * rs * g.y + b.y;
  o.z = s.z + (v.z - mu) * rs * g.z + b.z;
  o.w = s.w + (v.w - mu) * rs * g.w + b.w;
  *(float4*)&y[base] = o;
}

// ---------------------------------------------------------------------------
// Fused FFN fallback (used when ws is too small for the hidden tensor).
// ---------------------------------------------------------------------------
__global__ __launch_bounds__(512) void ffn_mfma_kernel(
    const unsigned short* __restrict__ SB, const unsigned short* __restrict__ MSG,
    const unsigned short* __restrict__ W1t, const unsigned short* __restrict__ W2t,
    const float* __restrict__ g2, const float* __restrict__ b2,
    const float* __restrict__ src, float* __restrict__ out) {
  __shared__ __align__(16) unsigned short As[64 * 32];
  __shared__ __align__(16) unsigned short W1s[128 * 32];
  __shared__ __align__(16) unsigned short hid[64 * 128];
  __shared__ __align__(16) unsigned short W2s[256 * 32];
  __shared__ float redS[64][5], redQ[64][5];
  const int tid = threadIdx.x;
  const int wv = tid >> 6, l = tid & 63;
  const int wr = wv >> 2, wc = wv & 3;
  const int lr = l & 15, lq = l >> 4;
  const int m0 = blockIdx.x * 64;
  char* hidb = (char*)hid;

  f32x4_t acc[2][4];
#pragma unroll
  for (int m = 0; m < 2; m++)
#pragma unroll
    for (int n = 0; n < 4; n++) acc[m][n] = (f32x4_t){0.f, 0.f, 0.f, 0.f};

  for (int hc = 0; hc < 2048; hc += 128) {
    f32x4_t acc2[2][2];
#pragma unroll
    for (int m = 0; m < 2; m++)
#pragma unroll
      for (int n = 0; n < 2; n++) acc2[m][n] = (f32x4_t){0.f, 0.f, 0.f, 0.f};

    for (int ks = 0; ks < 16; ks++) {
      int k0 = ks * 32;
      if (tid < 256) {
        int r = tid >> 2, s = tid & 3;
        int q = s ^ ((r >> 1) & 3);
        const unsigned short* base = (k0 < 256)
            ? &SB[(size_t)(m0 + r) * CC + k0 + q * 8]
            : &MSG[(size_t)(m0 + r) * CC + (k0 - 256) + q * 8];
        *(uint4*)&As[r * 32 + s * 8] = *(const uint4*)base;
      }
      {
        int r = tid >> 2, s = tid & 3;
        int q = s ^ ((r >> 1) & 3);
        *(uint4*)&W1s[r * 32 + s * 8] = *(const uint4*)&W1t[(size_t)(hc + r) * 512 + k0 + q * 8];
      }
      __syncthreads();
      bf16x8_t af[2], b1f[2];
#pragma unroll
      for (int m = 0; m < 2; m++) {
        int r = wr * 32 + m * 16 + lr;
        int s = lq ^ ((r >> 1) & 3);
        af[m] = *(const bf16x8_t*)&As[r * 32 + s * 8];
      }
#pragma unroll
      for (int n = 0; n < 2; n++) {
        int r = wc * 32 + n * 16 + lr;
        int s = lq ^ ((r >> 1) & 3);
        b1f[n] = *(const bf16x8_t*)&W1s[r * 32 + s * 8];
      }
#pragma unroll
      for (int m = 0; m < 2; m++)
#pragma unroll
        for (int n = 0; n < 2; n++)
          acc2[m][n] = __builtin_amdgcn_mfma_f32_16x16x32_bf16(af[m], b1f[n], acc2[m][n], 0, 0, 0);
      __syncthreads();
    }

#pragma unroll
    for (int m = 0; m < 2; m++)
#pragma unroll
      for (int n = 0; n < 2; n++)
#pragma unroll
        for (int j = 0; j < 4; j++) {
          int row = wr * 32 + m * 16 + lq * 4 + j;
          int col = wc * 32 + n * 16 + lr;
          float x = acc2[m][n][j];
          float gl = 0.5f * x * (1.0f + erff(x * 0.70710678118654752f));
          int byte = (row * 256 + col * 2) ^ ((row & 7) << 4);
          *(unsigned short*)(hidb + byte) = f2bf(gl);
        }
    __syncthreads();

#pragma unroll
    for (int ks2 = 0; ks2 < 4; ks2++) {
      int kg = hc + ks2 * 32;
#pragma unroll
      for (int it = 0; it < 2; it++) {
        int lin = it * 512 + tid;
        int r = lin >> 2, s = lin & 3;
        int q = s ^ ((r >> 1) & 3);
        *(uint4*)&W2s[r * 32 + s * 8] = *(const uint4*)&W2t[(size_t)r * 2048 + kg + q * 8];
      }
      __syncthreads();
      bf16x8_t ah[2], b2f[4];
#pragma unroll
      for (int m = 0; m < 2; m++) {
        int row = wr * 32 + m * 16 + lr;
        int byte = (row * 256 + ks2 * 64 + lq * 16) ^ ((row & 7) << 4);
        ah[m] = *(const bf16x8_t*)(hidb + byte);
      }
#pragma unroll
      for (int n = 0; n < 4; n++) {
        int r = wc * 64 + n * 16 + lr;
        int s = lq ^ ((r >> 1) & 3);
        b2f[n] = *(const bf16x8_t*)&W2s[r * 32 + s * 8];
      }
#pragma unroll
      for (int m = 0; m < 2; m++)
#pragma unroll
        for (int n = 0; n < 4; n++)
          acc[m][n] = __builtin_amdgcn_mfma_f32_16x16x32_bf16(ah[m], b2f[n], acc[m][n], 0, 0, 0);
      __syncthreads();
    }
  }

  float s1[2][4], s2[2][4];
#pragma unroll
  for (int m = 0; m < 2; m++)
#pragma unroll
    for (int j = 0; j < 4; j++) {
      float a = 0.f, b = 0.f;
#pragma unroll
      for (int n = 0; n < 4; n++) { float x = acc[m][n][j]; a += x; b += x * x; }
      s1[m][j] = a; s2[m][j] = b;
    }
#pragma unroll
  for (int mask = 1; mask < 16; mask <<= 1)
#pragma unroll
    for (int m = 0; m < 2; m++)
#pragma unroll
      for (int j = 0; j < 4; j++) {
        s1[m][j] += __shfl_xor(s1[m][j], mask, 64);
        s2[m][j] += __shfl_xor(s2[m][j], mask, 64);
      }
  if (lr == 0) {
#pragma unroll
    for (int m = 0; m < 2; m++)
#pragma unroll
      for (int j = 0; j < 4; j++) {
        int rl = wr * 32 + m * 16 + lq * 4 + j;
        redS[rl][wc] = s1[m][j];
        redQ[rl][wc] = s2[m][j];
      }
  }
  __syncthreads();
#pragma unroll
  for (int m = 0; m < 2; m++)
#pragma unroll
    for (int j = 0; j < 4; j++) {
      int rl = wr * 32 + m * 16 + lq * 4 + j;
      float ts = redS[rl][0] + redS[rl][1] + redS[rl][2] + redS[rl][3];
      float tq = redQ[rl][0] + redQ[rl][1] + redQ[rl][2] + redQ[rl][3];
      float mu = ts * (1.f / 256.f);
      float var = tq * (1.f / 256.f) - mu * mu;
      float rs = rsqrtf(var + LN_EPS);
      size_t rowg = (size_t)(m0 + rl);
#pragma unroll
      for (int n = 0; n < 4; n++) {
        int col = wc * 64 + n * 16 + lr;
        float v = src[rowg * CC + col] + (acc[m][n][j] - mu) * rs * g2[col] + b2[col];
        out[rowg * CC + col] = v;
      }
    }
}

extern "C" void kernel_launch(void* const* d_in, const int* in_sizes, int n_in,
                              void* d_out, int out_size, void* d_ws, size_t ws_size,
                              hipStream_t stream) {
  const float* source = (const float*)d_in[0];
  const float* target = (const float*)d_in[1];
  const float* weights = (const float*)d_in[2];
  const float* conf   = (const float*)d_in[3];
  const float* Wq = (const float*)d_in[4];
  const float* Wk = (const float*)d_in[5];
  const float* Wv = (const float*)d_in[6];
  const float* Wm = (const float*)d_in[7];
  const float* g1 = (const float*)d_in[8];
  const float* b1 = (const float*)d_in[9];
  const float* Wf1 = (const float*)d_in[10];
  const float* Wf2 = (const float*)d_in[11];
  const float* g2 = (const float*)d_in[12];
  const float* b2 = (const float*)d_in[13];
  float* out = (float*)d_out;

  unsigned short* SB   = (unsigned short*)d_ws;                 // [16384][256]
  unsigned short* MSGb = SB + (size_t)T_TOK * CC;               // [16384][256]
  unsigned short* Mt   = MSGb + (size_t)T_TOK * CC;             // [2048][256]
  unsigned short* WMt  = Mt + (size_t)2048 * 256;               // [256][256]
  unsigned short* WF1t = WMt + (size_t)256 * 256;               // [2048][512]
  unsigned short* WF2t = WF1t + (size_t)2048 * 512;             // [256][2048]
  unsigned short* BIG  = WF2t + (size_t)256 * 2048;             // QKc / hid overlap
  unsigned short* QKc  = BIG;                                   // [2048][2048]
  unsigned short* hid  = BIG;                                   // [16384][2048]
  unsigned short* AObf = (unsigned short*)d_out;                // parked in d_out

  size_t need_unfused = ((size_t)(BIG - SB) + (size_t)T_TOK * 2048) * sizeof(unsigned short);
  bool unfused = ws_size >= need_unfused;

  // prep
  cvt_bf16_kernel<<<T_TOK * CC / 1024, 256, 0, stream>>>(source, SB);
  transpose_cvt_kernel<<<dim3(4, 4), 256, 0, stream>>>(Wm, WMt, 256, 256);
  transpose_cvt_kernel<<<dim3(8, 32), 256, 0, stream>>>(Wf1, WF1t, 512, 2048);
  transpose_cvt_kernel<<<dim3(32, 4), 256, 0, stream>>>(Wf2, WF2t, 2048, 256);
  precM_kernel<<<2048, 256, 0, stream>>>(Wq, Wk, Mt);

  // attention pipeline, chunked
  for (int c = 0; c < T_TOK / CHUNK; c++) {
    int t0 = c * CHUNK;
    mfma_gemm_kernel<0><<<dim3(CHUNK / 64, 8), 512, 0, stream>>>(
        SB + (size_t)t0 * CC, Mt, QKc, nullptr, nullptr, 256, 2048);
    attn_kernel<<<CHUNK / 4, 256, 0, stream>>>(QKc, target, weights, conf, Wv, AObf, t0);
  }
  // message = LN(AO @ Wm)
  mfma_gemm_kernel<1><<<dim3(T_TOK / 64, 1), 512, 0, stream>>>(
      AObf, WMt, MSGb, g1, b1, 256, 256);

  if (unfused) {
    gemm1_kernel<<<dim3(T_TOK / 128, 16), 256, 0, stream>>>(SB, MSGb, WF1t, hid);
    gemm2_kernel<<<dim3(T_TOK / 64, 2), 256, 0, stream>>>(hid, WF2t, out);
    ln_res_kernel<<<T_TOK / 4, 256, 0, stream>>>(out, source, g2, b2);
  } else {
    ffn_mfma_kernel<<<T_TOK / 64, 512, 0, stream>>>(SB, MSGb, WF1t, WF2t, g2, b2, source, out);
  }
}

// Round 5
// 469.570 us; speedup vs baseline: 1.4184x; 1.2029x over previous
//
#include <hip/hip_runtime.h>
#include <hip/hip_bf16.h>
#include <math.h>

#define T_TOK 16384
#define CC 256
#define PP 16
#define HH 8
#define DD 32
#define LN_EPS 1e-5f
#define CHUNK 2048

typedef __attribute__((ext_vector_type(8))) short bf16x8_t;
typedef __attribute__((ext_vector_type(4))) float f32x4_t;

__device__ __forceinline__ unsigned short f2bf(float x) {
  __hip_bfloat16 h = __float2bfloat16(x);
  return *reinterpret_cast<unsigned short*>(&h);
}
__device__ __forceinline__ float bf2f(unsigned short u) {
  union { unsigned int i; float f; } v; v.i = ((unsigned int)u) << 16; return v.f;
}

// ---------------------------------------------------------------------------
// Prep kernels
// ---------------------------------------------------------------------------
__global__ __launch_bounds__(256) void cvt_bf16_kernel(const float* __restrict__ src,
                                                       unsigned short* __restrict__ dst) {
  int i = (blockIdx.x * 256 + threadIdx.x) * 4;
  float4 v = *(const float4*)&src[i];
  ushort4 o = make_ushort4(f2bf(v.x), f2bf(v.y), f2bf(v.z), f2bf(v.w));
  *(ushort4*)&dst[i] = o;
}

__global__ __launch_bounds__(256) void transpose_cvt_kernel(const float* __restrict__ src,
                                                            unsigned short* __restrict__ dst,
                                                            int K, int N) {
  __shared__ float tile[64][65];
  int k0 = blockIdx.x * 64, n0 = blockIdx.y * 64;
  int tid = threadIdx.x;
#pragma unroll
  for (int i = 0; i < 16; i++) {
    int lin = i * 256 + tid, r = lin >> 6, c = lin & 63;
    tile[r][c] = src[(size_t)(k0 + r) * N + n0 + c];
  }
  __syncthreads();
#pragma unroll
  for (int i = 0; i < 16; i++) {
    int lin = i * 256 + tid, n = lin >> 6, k = lin & 63;
    dst[(size_t)(n0 + n) * K + k0 + k] = f2bf(tile[k][n]);
  }
}

// Mt[(h*256+e)][c] = bf16( sum_d Wq[c][h*32+d] * Wk[e][h*32+d] )
// LDS-staged, coalesced. grid = 16 blocks: h = b>>1, e-half = b&1.
__global__ __launch_bounds__(256) void precM_kernel(const float* __restrict__ Wq,
                                                    const float* __restrict__ Wk,
                                                    unsigned short* __restrict__ Mt) {
  __shared__ float wqS[256][33];
  __shared__ float wkS[128][33];
  const int tid = threadIdx.x;
  const int h = blockIdx.x >> 1, eh = blockIdx.x & 1;
  // stage Wq[:, h*32:h*32+32]  (8192 elems)
#pragma unroll
  for (int it = 0; it < 32; it++) {
    int lin = it * 256 + tid, r = lin >> 5, d = lin & 31;
    wqS[r][d] = Wq[(size_t)r * CC + h * DD + d];
  }
  // stage Wk[eh*128 : +128, h*32:+32]  (4096 elems)
#pragma unroll
  for (int it = 0; it < 16; it++) {
    int lin = it * 256 + tid, r = lin >> 5, d = lin & 31;
    wkS[r][d] = Wk[(size_t)(eh * 128 + r) * CC + h * DD + d];
  }
  __syncthreads();
  const int w = tid >> 6, l = tid & 63;
  for (int ei = 0; ei < 32; ei++) {
    int e = w * 32 + ei;
    float o[4] = {0.f, 0.f, 0.f, 0.f};
#pragma unroll
    for (int d = 0; d < 32; d++) {
      float kv = wkS[e][d];
      o[0] += kv * wqS[l][d];
      o[1] += kv * wqS[l + 64][d];
      o[2] += kv * wqS[l + 128][d];
      o[3] += kv * wqS[l + 192][d];
    }
    size_t rowb = (size_t)(h * 256 + eh * 128 + e) * CC;
    Mt[rowb + l] = f2bf(o[0]);
    Mt[rowb + l + 64] = f2bf(o[1]);
    Mt[rowb + l + 128] = f2bf(o[2]);
    Mt[rowb + l + 192] = f2bf(o[3]);
  }
}

// ---------------------------------------------------------------------------
// MFMA GEMM: Out[M,*] = A[M,K] @ Bt^T  (Bt [N][K] bf16), BM=64 BN=256 BK=32.
// EPI 0: bf16 store. EPI 1: LN(g,b) -> bf16.
// ---------------------------------------------------------------------------
template<int EPI>
__global__ __launch_bounds__(512) void mfma_gemm_kernel(
    const unsigned short* __restrict__ A, const unsigned short* __restrict__ Bt,
    unsigned short* __restrict__ Out, const float* __restrict__ gam,
    const float* __restrict__ bet, int K, int strideO) {
  __shared__ __align__(16) unsigned short As[2][64 * 32];
  __shared__ __align__(16) unsigned short Bs[2][256 * 32];
  __shared__ float redS[64][5], redQ[64][5];
  const int tid = threadIdx.x;
  const int wv = tid >> 6, l = tid & 63;
  const int wr = wv >> 2, wc = wv & 3;
  const int lr = l & 15, lq = l >> 4;
  const int m0 = blockIdx.x * 64;
  const int n0 = blockIdx.y * 256;
  const int nsteps = K >> 5;

  f32x4_t acc[2][4];
#pragma unroll
  for (int m = 0; m < 2; m++)
#pragma unroll
    for (int n = 0; n < 4; n++) acc[m][n] = (f32x4_t){0.f, 0.f, 0.f, 0.f};

  uint4 aReg; uint4 bReg[2];
  if (tid < 256) {
    int r = tid >> 2, s = tid & 3, q = s ^ ((r >> 1) & 3);
    aReg = *(const uint4*)&A[(size_t)(m0 + r) * K + q * 8];
    *(uint4*)&As[0][r * 32 + s * 8] = aReg;
  }
#pragma unroll
  for (int it = 0; it < 2; it++) {
    int lin = it * 512 + tid, r = lin >> 2, s = lin & 3, q = s ^ ((r >> 1) & 3);
    bReg[it] = *(const uint4*)&Bt[(size_t)(n0 + r) * K + q * 8];
    *(uint4*)&Bs[0][r * 32 + s * 8] = bReg[it];
  }
  __syncthreads();

  for (int st = 0; st < nsteps; st++) {
    int cur = st & 1;
    bool pf = (st + 1) < nsteps;
    if (pf) {
      int kn = (st + 1) * 32;
      if (tid < 256) {
        int r = tid >> 2, s = tid & 3, q = s ^ ((r >> 1) & 3);
        aReg = *(const uint4*)&A[(size_t)(m0 + r) * K + kn + q * 8];
      }
#pragma unroll
      for (int it = 0; it < 2; it++) {
        int lin = it * 512 + tid, r = lin >> 2, s = lin & 3, q = s ^ ((r >> 1) & 3);
        bReg[it] = *(const uint4*)&Bt[(size_t)(n0 + r) * K + kn + q * 8];
      }
    }
    bf16x8_t af[2], bfr[4];
#pragma unroll
    for (int m = 0; m < 2; m++) {
      int r = wr * 32 + m * 16 + lr;
      int s = lq ^ ((r >> 1) & 3);
      af[m] = *(const bf16x8_t*)&As[cur][r * 32 + s * 8];
    }
#pragma unroll
    for (int n = 0; n < 4; n++) {
      int r = wc * 64 + n * 16 + lr;
      int s = lq ^ ((r >> 1) & 3);
      bfr[n] = *(const bf16x8_t*)&Bs[cur][r * 32 + s * 8];
    }
#pragma unroll
    for (int m = 0; m < 2; m++)
#pragma unroll
      for (int n = 0; n < 4; n++)
        acc[m][n] = __builtin_amdgcn_mfma_f32_16x16x32_bf16(af[m], bfr[n], acc[m][n], 0, 0, 0);
    if (pf) {
      if (tid < 256) {
        int r = tid >> 2, s = tid & 3;
        *(uint4*)&As[cur ^ 1][r * 32 + s * 8] = aReg;
      }
#pragma unroll
      for (int it = 0; it < 2; it++) {
        int lin = it * 512 + tid, r = lin >> 2, s = lin & 3;
        *(uint4*)&Bs[cur ^ 1][r * 32 + s * 8] = bReg[it];
      }
    }
    __syncthreads();
  }

  if constexpr (EPI == 0) {
#pragma unroll
    for (int m = 0; m < 2; m++)
#pragma unroll
      for (int n = 0; n < 4; n++)
#pragma unroll
        for (int j = 0; j < 4; j++) {
          int rl = wr * 32 + m * 16 + lq * 4 + j;
          int col = n0 + wc * 64 + n * 16 + lr;
          Out[(size_t)(m0 + rl) * strideO + col] = f2bf(acc[m][n][j]);
        }
  } else {
    float s1[2][4], s2[2][4];
#pragma unroll
    for (int m = 0; m < 2; m++)
#pragma unroll
      for (int j = 0; j < 4; j++) {
        float a = 0.f, b = 0.f;
#pragma unroll
        for (int n = 0; n < 4; n++) { float x = acc[m][n][j]; a += x; b += x * x; }
        s1[m][j] = a; s2[m][j] = b;
      }
#pragma unroll
    for (int mask = 1; mask < 16; mask <<= 1)
#pragma unroll
      for (int m = 0; m < 2; m++)
#pragma unroll
        for (int j = 0; j < 4; j++) {
          s1[m][j] += __shfl_xor(s1[m][j], mask, 64);
          s2[m][j] += __shfl_xor(s2[m][j], mask, 64);
        }
    if (lr == 0) {
#pragma unroll
      for (int m = 0; m < 2; m++)
#pragma unroll
        for (int j = 0; j < 4; j++) {
          int rl = wr * 32 + m * 16 + lq * 4 + j;
          redS[rl][wc] = s1[m][j];
          redQ[rl][wc] = s2[m][j];
        }
    }
    __syncthreads();
#pragma unroll
    for (int m = 0; m < 2; m++)
#pragma unroll
      for (int j = 0; j < 4; j++) {
        int rl = wr * 32 + m * 16 + lq * 4 + j;
        float ts = redS[rl][0] + redS[rl][1] + redS[rl][2] + redS[rl][3];
        float tq = redQ[rl][0] + redQ[rl][1] + redQ[rl][2] + redQ[rl][3];
        float mu = ts * (1.f / 256.f);
        float var = tq * (1.f / 256.f) - mu * mu;
        float rs = rsqrtf(var + LN_EPS);
#pragma unroll
        for (int n = 0; n < 4; n++) {
          int col = wc * 64 + n * 16 + lr;
          float v = (acc[m][n][j] - mu) * rs * gam[col] + bet[col];
          Out[(size_t)(m0 + rl) * strideO + col] = f2bf(v);
        }
      }
  }
}

// ---------------------------------------------------------------------------
// Attention: 4 waves = 4 tokens per block. Phase-5 block-cooperative; the
// phase-5 partial buffer reuses tcl's LDS (sync-guarded) -> 38KB total.
// ---------------------------------------------------------------------------
__global__ __launch_bounds__(256) void attn_kernel(const unsigned short* __restrict__ QKc,
                                                   const float* __restrict__ target,
                                                   const float* __restrict__ wts,
                                                   const float* __restrict__ conf,
                                                   const float* __restrict__ Wv,
                                                   unsigned short* __restrict__ AO,
                                                   int t0) {
  __shared__ float scL[4][HH][PP];
  __shared__ float awL[4][HH][PP];
  __shared__ float tcl[4][HH][260];
  float (*prS)[4][256] = (float (*)[4][256])&tcl[0][0][0];  // reused after sync
  const int tid = threadIdx.x;
  const int w = tid >> 6, l = tid & 63;
  const int tl = blockIdx.x * 4 + w;
  const int t = t0 + tl;
  const float* trow = target + (size_t)t * PP * CC;

  float qk[HH][4];
  const unsigned short* qkrow = QKc + (size_t)tl * 2048;
#pragma unroll
  for (int h = 0; h < HH; h++) {
    ushort4 u = *(const ushort4*)&qkrow[h * 256 + 4 * l];
    qk[h][0] = bf2f(u.x); qk[h][1] = bf2f(u.y); qk[h][2] = bf2f(u.z); qk[h][3] = bf2f(u.w);
  }
  float4 tv[PP];
#pragma unroll
  for (int p = 0; p < PP; p++) tv[p] = *(const float4*)&trow[p * CC + 4 * l];

  const float rsD = 0.17677669529663687f;
#pragma unroll
  for (int p = 0; p < PP; p++) {
    float part[HH];
#pragma unroll
    for (int h = 0; h < HH; h++)
      part[h] = qk[h][0] * tv[p].x + qk[h][1] * tv[p].y + qk[h][2] * tv[p].z + qk[h][3] * tv[p].w;
#pragma unroll
    for (int m = 1; m < 64; m <<= 1)
#pragma unroll
      for (int h = 0; h < HH; h++) part[h] += __shfl_xor(part[h], m, 64);
    if (l == 0) {
      float wscale = wts[(size_t)t * PP + p] * rsD;
#pragma unroll
      for (int h = 0; h < HH; h++) scL[w][h][p] = part[h] * wscale;
    }
  }
  __syncthreads();

  {
    int p = l & 15;
    int h0 = l >> 4, h1 = h0 + 4;
    float cf = conf[(size_t)t * PP + p];
    float x0 = scL[w][h0][p], x1 = scL[w][h1][p];
    float m0 = x0, m1 = x1;
#pragma unroll
    for (int m = 1; m < 16; m <<= 1) {
      m0 = fmaxf(m0, __shfl_xor(m0, m, 64));
      m1 = fmaxf(m1, __shfl_xor(m1, m, 64));
    }
    float e0 = expf(x0 - m0), e1 = expf(x1 - m1);
    float s0 = e0, s1 = e1;
#pragma unroll
    for (int m = 1; m < 16; m <<= 1) {
      s0 += __shfl_xor(s0, m, 64);
      s1 += __shfl_xor(s1, m, 64);
    }
    awL[w][h0][p] = e0 / s0 * cf;
    awL[w][h1][p] = e1 / s1 * cf;
  }
  __syncthreads();

  float tc_[HH][4];
#pragma unroll
  for (int h = 0; h < HH; h++)
#pragma unroll
    for (int j = 0; j < 4; j++) tc_[h][j] = 0.f;
#pragma unroll
  for (int p = 0; p < PP; p++) {
#pragma unroll
    for (int h = 0; h < HH; h++) {
      float aw = awL[w][h][p];
      tc_[h][0] += aw * tv[p].x; tc_[h][1] += aw * tv[p].y;
      tc_[h][2] += aw * tv[p].z; tc_[h][3] += aw * tv[p].w;
    }
  }
#pragma unroll
  for (int h = 0; h < HH; h++)
    *(float4*)&tcl[w][h][4 * l] = make_float4(tc_[h][0], tc_[h][1], tc_[h][2], tc_[h][3]);
  __syncthreads();

  // ---- phase 5: e-split across waves, 4 tokens batched ----
  const int hh = l >> 3;
  float po[4][4];
#pragma unroll
  for (int tok = 0; tok < 4; tok++)
#pragma unroll
    for (int j = 0; j < 4; j++) po[tok][j] = 0.f;
  const float* wvb = Wv + (size_t)(w * 64) * CC + 4 * l;
#pragma unroll 8
  for (int e = 0; e < 64; e += 2) {
    float4 w0 = *(const float4*)&wvb[(size_t)e * CC];
    float4 w1 = *(const float4*)&wvb[(size_t)(e + 1) * CC];
    int eg = w * 64 + e;
#pragma unroll
    for (int tok = 0; tok < 4; tok++) {
      float2 tp = *(const float2*)&tcl[tok][hh][eg];
      po[tok][0] += tp.x * w0.x + tp.y * w1.x;
      po[tok][1] += tp.x * w0.y + tp.y * w1.y;
      po[tok][2] += tp.x * w0.z + tp.y * w1.z;
      po[tok][3] += tp.x * w0.w + tp.y * w1.w;
    }
  }
  __syncthreads();   // all tcl reads done; safe to overwrite with partials
#pragma unroll
  for (int tok = 0; tok < 4; tok++)
    *(float4*)&prS[w][tok][4 * l] = make_float4(po[tok][0], po[tok][1], po[tok][2], po[tok][3]);
  __syncthreads();
  {
    int tok = tid >> 6;
    int cb = (tid & 63) * 4;
    float4 a0 = *(const float4*)&prS[0][tok][cb];
    float4 a1 = *(const float4*)&prS[1][tok][cb];
    float4 a2 = *(const float4*)&prS[2][tok][cb];
    float4 a3 = *(const float4*)&prS[3][tok][cb];
    float ox = a0.x + a1.x + a2.x + a3.x;
    float oy = a0.y + a1.y + a2.y + a3.y;
    float oz = a0.z + a1.z + a2.z + a3.z;
    float ow = a0.w + a1.w + a2.w + a3.w;
    int tg = t0 + blockIdx.x * 4 + tok;
    *(ushort4*)&AO[(size_t)tg * CC + cb] = make_ushort4(f2bf(ox), f2bf(oy), f2bf(oz), f2bf(ow));
  }
}

// ---------------------------------------------------------------------------
// FFN GEMM1: hid = gelu([SB||MSG] @ W1t^T), bf16. BM=128 BN=128, 256 thr.
// ---------------------------------------------------------------------------
__global__ __launch_bounds__(256) void gemm1_kernel(
    const unsigned short* __restrict__ SB, const unsigned short* __restrict__ MSG,
    const unsigned short* __restrict__ W1t, unsigned short* __restrict__ hid) {
  __shared__ __align__(16) unsigned short As[2][128 * 32];
  __shared__ __align__(16) unsigned short Bs[2][128 * 32];
  const int tid = threadIdx.x;
  const int wv = tid >> 6, l = tid & 63;
  const int wr = wv >> 1, wc = wv & 1;
  const int lr = l & 15, lq = l >> 4;
  const int m0 = blockIdx.x * 128;
  const int n0 = blockIdx.y * 128;

  f32x4_t acc[4][4];
#pragma unroll
  for (int m = 0; m < 4; m++)
#pragma unroll
    for (int n = 0; n < 4; n++) acc[m][n] = (f32x4_t){0.f, 0.f, 0.f, 0.f};

  uint4 aR[2], bR[2];
#pragma unroll
  for (int it = 0; it < 2; it++) {
    int lin = it * 256 + tid, r = lin >> 2, s = lin & 3, q = s ^ ((r >> 1) & 3);
    aR[it] = *(const uint4*)&SB[(size_t)(m0 + r) * CC + q * 8];
    *(uint4*)&As[0][r * 32 + s * 8] = aR[it];
    bR[it] = *(const uint4*)&W1t[(size_t)(n0 + r) * 512 + q * 8];
    *(uint4*)&Bs[0][r * 32 + s * 8] = bR[it];
  }
  __syncthreads();

  for (int st = 0; st < 16; st++) {
    int cur = st & 1;
    bool pf = st < 15;
    if (pf) {
      int kn = (st + 1) * 32;
#pragma unroll
      for (int it = 0; it < 2; it++) {
        int lin = it * 256 + tid, r = lin >> 2, s = lin & 3, q = s ^ ((r >> 1) & 3);
        int ka = kn + q * 8;
        const unsigned short* ap = (ka < 256) ? &SB[(size_t)(m0 + r) * CC + ka]
                                              : &MSG[(size_t)(m0 + r) * CC + ka - 256];
        aR[it] = *(const uint4*)ap;
        bR[it] = *(const uint4*)&W1t[(size_t)(n0 + r) * 512 + kn + q * 8];
      }
    }
    bf16x8_t af[4], bf[4];
#pragma unroll
    for (int m = 0; m < 4; m++) {
      int r = wr * 64 + m * 16 + lr;
      int s = lq ^ ((r >> 1) & 3);
      af[m] = *(const bf16x8_t*)&As[cur][r * 32 + s * 8];
    }
#pragma unroll
    for (int n = 0; n < 4; n++) {
      int r = wc * 64 + n * 16 + lr;
      int s = lq ^ ((r >> 1) & 3);
      bf[n] = *(const bf16x8_t*)&Bs[cur][r * 32 + s * 8];
    }
#pragma unroll
    for (int m = 0; m < 4; m++)
#pragma unroll
      for (int n = 0; n < 4; n++)
        acc[m][n] = __builtin_amdgcn_mfma_f32_16x16x32_bf16(af[m], bf[n], acc[m][n], 0, 0, 0);
    if (pf) {
#pragma unroll
      for (int it = 0; it < 2; it++) {
        int lin = it * 256 + tid, r = lin >> 2, s = lin & 3;
        *(uint4*)&As[cur ^ 1][r * 32 + s * 8] = aR[it];
        *(uint4*)&Bs[cur ^ 1][r * 32 + s * 8] = bR[it];
      }
    }
    __syncthreads();
  }

#pragma unroll
  for (int m = 0; m < 4; m++)
#pragma unroll
    for (int n = 0; n < 4; n++)
#pragma unroll
      for (int j = 0; j < 4; j++) {
        int row = m0 + wr * 64 + m * 16 + lq * 4 + j;
        int col = n0 + wc * 64 + n * 16 + lr;
        float x = acc[m][n][j];
        float gl = 0.5f * x * (1.0f + erff(x * 0.70710678118654752f));
        hid[(size_t)row * 2048 + col] = f2bf(gl);
      }
}

// ---------------------------------------------------------------------------
// FFN GEMM2: raw = hid @ W2t^T, f32 to d_out. BM=64 BN=128, 256 thr.
// ---------------------------------------------------------------------------
__global__ __launch_bounds__(256) void gemm2_kernel(
    const unsigned short* __restrict__ hid, const unsigned short* __restrict__ W2t,
    float* __restrict__ outRaw) {
  __shared__ __align__(16) unsigned short As[2][64 * 32];
  __shared__ __align__(16) unsigned short Bs[2][128 * 32];
  const int tid = threadIdx.x;
  const int wv = tid >> 6, l = tid & 63;
  const int wr = wv >> 1, wc = wv & 1;
  const int lr = l & 15, lq = l >> 4;
  const int m0 = blockIdx.x * 64;
  const int n0 = blockIdx.y * 128;

  f32x4_t acc[2][4];
#pragma unroll
  for (int m = 0; m < 2; m++)
#pragma unroll
    for (int n = 0; n < 4; n++) acc[m][n] = (f32x4_t){0.f, 0.f, 0.f, 0.f};

  uint4 aR, bR[2];
  {
    int r = tid >> 2, s = tid & 3, q = s ^ ((r >> 1) & 3);
    aR = *(const uint4*)&hid[(size_t)(m0 + r) * 2048 + q * 8];
    *(uint4*)&As[0][r * 32 + s * 8] = aR;
  }
#pragma unroll
  for (int it = 0; it < 2; it++) {
    int lin = it * 256 + tid, r = lin >> 2, s = lin & 3, q = s ^ ((r >> 1) & 3);
    bR[it] = *(const uint4*)&W2t[(size_t)(n0 + r) * 2048 + q * 8];
    *(uint4*)&Bs[0][r * 32 + s * 8] = bR[it];
  }
  __syncthreads();

  for (int st = 0; st < 64; st++) {
    int cur = st & 1;
    bool pf = st < 63;
    if (pf) {
      int kn = (st + 1) * 32;
      {
        int r = tid >> 2, s = tid & 3, q = s ^ ((r >> 1) & 3);
        aR = *(const uint4*)&hid[(size_t)(m0 + r) * 2048 + kn + q * 8];
      }
#pragma unroll
      for (int it = 0; it < 2; it++) {
        int lin = it * 256 + tid, r = lin >> 2, s = lin & 3, q = s ^ ((r >> 1) & 3);
        bR[it] = *(const uint4*)&W2t[(size_t)(n0 + r) * 2048 + kn + q * 8];
      }
    }
    bf16x8_t af[2], bf[4];
#pragma unroll
    for (int m = 0; m < 2; m++) {
      int r = wr * 32 + m * 16 + lr;
      int s = lq ^ ((r >> 1) & 3);
      af[m] = *(const bf16x8_t*)&As[cur][r * 32 + s * 8];
    }
#pragma unroll
    for (int n = 0; n < 4; n++) {
      int r = wc * 64 + n * 16 + lr;
      int s = lq ^ ((r >> 1) & 3);
      bf[n] = *(const bf16x8_t*)&Bs[cur][r * 32 + s * 8];
    }
#pragma unroll
    for (int m = 0; m < 2; m++)
#pragma unroll
      for (int n = 0; n < 4; n++)
        acc[m][n] = __builtin_amdgcn_mfma_f32_16x16x32_bf16(af[m], bf[n], acc[m][n], 0, 0, 0);
    if (pf) {
      {
        int r = tid >> 2, s = tid & 3;
        *(uint4*)&As[cur ^ 1][r * 32 + s * 8] = aR;
      }
#pragma unroll
      for (int it = 0; it < 2; it++) {
        int lin = it * 256 + tid, r = lin >> 2, s = lin & 3;
        *(uint4*)&Bs[cur ^ 1][r * 32 + s * 8] = bR[it];
      }
    }
    __syncthreads();
  }

#pragma unroll
  for (int m = 0; m < 2; m++)
#pragma unroll
    for (int n = 0; n < 4; n++)
#pragma unroll
      for (int j = 0; j < 4; j++) {
        int row = m0 + wr * 32 + m * 16 + lq * 4 + j;
        int col = n0 + wc * 64 + n * 16 + lr;
        outRaw[(size_t)row * CC + col] = acc[m][n][j];
      }
}

// LN + residual over raw f32 rows, in place on d_out.
__global__ __launch_bounds__(256) void ln_res_kernel(float* __restrict__ y,
                                                     const float* __restrict__ src,
                                                     const float* __restrict__ g2,
                                                     const float* __restrict__ b2) {
  const int l = threadIdx.x & 63;
  const int row = blockIdx.x * 4 + (threadIdx.x >> 6);
  size_t base = (size_t)row * CC + 4 * l;
  float4 v = *(const float4*)&y[base];
  float s1 = v.x + v.y + v.z + v.w;
  float s2 = v.x * v.x + v.y * v.y + v.z * v.z + v.w * v.w;
#pragma unroll
  for (int m = 1; m < 64; m <<= 1) {
    s1 += __shfl_xor(s1, m, 64);
    s2 += __shfl_xor(s2, m, 64);
  }
  float mu = s1 * (1.f / 256.f);
  float var = s2 * (1.f / 256.f) - mu * mu;
  float rs = rsqrtf(var + LN_EPS);
  float4 g = *(const float4*)&g2[4 * l];
  float4 b = *(const float4*)&b2[4 * l];
  float4 s = *(const float4*)&src[base];
  float4 o;
  o.x = s.x + (v.x - mu) * rs * g.x + b.x;
  o.y = s.y + (v.y - mu) * rs * g.y + b.y;
  o.z = s.z + (v.z - mu) * rs * g.z + b.z;
  o.w = s.w + (v.w - mu) * rs * g.w + b.w;
  *(float4*)&y[base] = o;
}

// ---------------------------------------------------------------------------
// Fused FFN fallback (only if ws too small for the hidden tensor).
// ---------------------------------------------------------------------------
__global__ __launch_bounds__(512) void ffn_mfma_kernel(
    const unsigned short* __restrict__ SB, const unsigned short* __restrict__ MSG,
    const unsigned short* __restrict__ W1t, const unsigned short* __restrict__ W2t,
    const float* __restrict__ g2, const float* __restrict__ b2,
    const float* __restrict__ src, float* __restrict__ out) {
  __shared__ __align__(16) unsigned short As[64 * 32];
  __shared__ __align__(16) unsigned short W1s[128 * 32];
  __shared__ __align__(16) unsigned short hid[64 * 128];
  __shared__ __align__(16) unsigned short W2s[256 * 32];
  __shared__ float redS[64][5], redQ[64][5];
  const int tid = threadIdx.x;
  const int wv = tid >> 6, l = tid & 63;
  const int wr = wv >> 2, wc = wv & 3;
  const int lr = l & 15, lq = l >> 4;
  const int m0 = blockIdx.x * 64;
  char* hidb = (char*)hid;

  f32x4_t acc[2][4];
#pragma unroll
  for (int m = 0; m < 2; m++)
#pragma unroll
    for (int n = 0; n < 4; n++) acc[m][n] = (f32x4_t){0.f, 0.f, 0.f, 0.f};

  for (int hc = 0; hc < 2048; hc += 128) {
    f32x4_t acc2[2][2];
#pragma unroll
    for (int m = 0; m < 2; m++)
#pragma unroll
      for (int n = 0; n < 2; n++) acc2[m][n] = (f32x4_t){0.f, 0.f, 0.f, 0.f};

    for (int ks = 0; ks < 16; ks++) {
      int k0 = ks * 32;
      if (tid < 256) {
        int r = tid >> 2, s = tid & 3;
        int q = s ^ ((r >> 1) & 3);
        const unsigned short* base = (k0 < 256)
            ? &SB[(size_t)(m0 + r) * CC + k0 + q * 8]
            : &MSG[(size_t)(m0 + r) * CC + (k0 - 256) + q * 8];
        *(uint4*)&As[r * 32 + s * 8] = *(const uint4*)base;
      }
      {
        int r = tid >> 2, s = tid & 3;
        int q = s ^ ((r >> 1) & 3);
        *(uint4*)&W1s[r * 32 + s * 8] = *(const uint4*)&W1t[(size_t)(hc + r) * 512 + k0 + q * 8];
      }
      __syncthreads();
      bf16x8_t af[2], b1f[2];
#pragma unroll
      for (int m = 0; m < 2; m++) {
        int r = wr * 32 + m * 16 + lr;
        int s = lq ^ ((r >> 1) & 3);
        af[m] = *(const bf16x8_t*)&As[r * 32 + s * 8];
      }
#pragma unroll
      for (int n = 0; n < 2; n++) {
        int r = wc * 32 + n * 16 + lr;
        int s = lq ^ ((r >> 1) & 3);
        b1f[n] = *(const bf16x8_t*)&W1s[r * 32 + s * 8];
      }
#pragma unroll
      for (int m = 0; m < 2; m++)
#pragma unroll
        for (int n = 0; n < 2; n++)
          acc2[m][n] = __builtin_amdgcn_mfma_f32_16x16x32_bf16(af[m], b1f[n], acc2[m][n], 0, 0, 0);
      __syncthreads();
    }

#pragma unroll
    for (int m = 0; m < 2; m++)
#pragma unroll
      for (int n = 0; n < 2; n++)
#pragma unroll
        for (int j = 0; j < 4; j++) {
          int row = wr * 32 + m * 16 + lq * 4 + j;
          int col = wc * 32 + n * 16 + lr;
          float x = acc2[m][n][j];
          float gl = 0.5f * x * (1.0f + erff(x * 0.70710678118654752f));
          int byte = (row * 256 + col * 2) ^ ((row & 7) << 4);
          *(unsigned short*)(hidb + byte) = f2bf(gl);
        }
    __syncthreads();

#pragma unroll
    for (int ks2 = 0; ks2 < 4; ks2++) {
      int kg = hc + ks2 * 32;
#pragma unroll
      for (int it = 0; it < 2; it++) {
        int lin = it * 512 + tid;
        int r = lin >> 2, s = lin & 3;
        int q = s ^ ((r >> 1) & 3);
        *(uint4*)&W2s[r * 32 + s * 8] = *(const uint4*)&W2t[(size_t)r * 2048 + kg + q * 8];
      }
      __syncthreads();
      bf16x8_t ah[2], b2f[4];
#pragma unroll
      for (int m = 0; m < 2; m++) {
        int row = wr * 32 + m * 16 + lr;
        int byte = (row * 256 + ks2 * 64 + lq * 16) ^ ((row & 7) << 4);
        ah[m] = *(const bf16x8_t*)(hidb + byte);
      }
#pragma unroll
      for (int n = 0; n < 4; n++) {
        int r = wc * 64 + n * 16 + lr;
        int s = lq ^ ((r >> 1) & 3);
        b2f[n] = *(const bf16x8_t*)&W2s[r * 32 + s * 8];
      }
#pragma unroll
      for (int m = 0; m < 2; m++)
#pragma unroll
        for (int n = 0; n < 4; n++)
          acc[m][n] = __builtin_amdgcn_mfma_f32_16x16x32_bf16(ah[m], b2f[n], acc[m][n], 0, 0, 0);
      __syncthreads();
    }
  }

  float s1[2][4], s2[2][4];
#pragma unroll
  for (int m = 0; m < 2; m++)
#pragma unroll
    for (int j = 0; j < 4; j++) {
      float a = 0.f, b = 0.f;
#pragma unroll
      for (int n = 0; n < 4; n++) { float x = acc[m][n][j]; a += x; b += x * x; }
      s1[m][j] = a; s2[m][j] = b;
    }
#pragma unroll
  for (int mask = 1; mask < 16; mask <<= 1)
#pragma unroll
    for (int m = 0; m < 2; m++)
#pragma unroll
      for (int j = 0; j < 4; j++) {
        s1[m][j] += __shfl_xor(s1[m][j], mask, 64);
        s2[m][j] += __shfl_xor(s2[m][j], mask, 64);
      }
  if (lr == 0) {
#pragma unroll
    for (int m = 0; m < 2; m++)
#pragma unroll
      for (int j = 0; j < 4; j++) {
        int rl = wr * 32 + m * 16 + lq * 4 + j;
        redS[rl][wc] = s1[m][j];
        redQ[rl][wc] = s2[m][j];
      }
  }
  __syncthreads();
#pragma unroll
  for (int m = 0; m < 2; m++)
#pragma unroll
    for (int j = 0; j < 4; j++) {
      int rl = wr * 32 + m * 16 + lq * 4 + j;
      float ts = redS[rl][0] + redS[rl][1] + redS[rl][2] + redS[rl][3];
      float tq = redQ[rl][0] + redQ[rl][1] + redQ[rl][2] + redQ[rl][3];
      float mu = ts * (1.f / 256.f);
      float var = tq * (1.f / 256.f) - mu * mu;
      float rs = rsqrtf(var + LN_EPS);
      size_t rowg = (size_t)(m0 + rl);
#pragma unroll
      for (int n = 0; n < 4; n++) {
        int col = wc * 64 + n * 16 + lr;
        float v = src[rowg * CC + col] + (acc[m][n][j] - mu) * rs * g2[col] + b2[col];
        out[rowg * CC + col] = v;
      }
    }
}

extern "C" void kernel_launch(void* const* d_in, const int* in_sizes, int n_in,
                              void* d_out, int out_size, void* d_ws, size_t ws_size,
                              hipStream_t stream) {
  const float* source = (const float*)d_in[0];
  const float* target = (const float*)d_in[1];
  const float* weights = (const float*)d_in[2];
  const float* conf   = (const float*)d_in[3];
  const float* Wq = (const float*)d_in[4];
  const float* Wk = (const float*)d_in[5];
  const float* Wv = (const float*)d_in[6];
  const float* Wm = (const float*)d_in[7];
  const float* g1 = (const float*)d_in[8];
  const float* b1 = (const float*)d_in[9];
  const float* Wf1 = (const float*)d_in[10];
  const float* Wf2 = (const float*)d_in[11];
  const float* g2 = (const float*)d_in[12];
  const float* b2 = (const float*)d_in[13];
  float* out = (float*)d_out;

  unsigned short* SB   = (unsigned short*)d_ws;                 // [16384][256]
  unsigned short* MSGb = SB + (size_t)T_TOK * CC;               // [16384][256]
  unsigned short* Mt   = MSGb + (size_t)T_TOK * CC;             // [2048][256]
  unsigned short* WMt  = Mt + (size_t)2048 * 256;               // [256][256]
  unsigned short* WF1t = WMt + (size_t)256 * 256;               // [2048][512]
  unsigned short* WF2t = WF1t + (size_t)2048 * 512;             // [256][2048]
  unsigned short* BIG  = WF2t + (size_t)256 * 2048;             // QKc / hid overlap
  unsigned short* QKc  = BIG;                                   // [16384][2048]
  unsigned short* hid  = BIG;                                   // [16384][2048]
  unsigned short* AObf = (unsigned short*)d_out;                // parked in d_out

  size_t need_big = ((size_t)(BIG - SB) + (size_t)T_TOK * 2048) * sizeof(unsigned short);
  bool big_ok = ws_size >= need_big;

  // prep
  cvt_bf16_kernel<<<T_TOK * CC / 1024, 256, 0, stream>>>(source, SB);
  transpose_cvt_kernel<<<dim3(4, 4), 256, 0, stream>>>(Wm, WMt, 256, 256);
  transpose_cvt_kernel<<<dim3(8, 32), 256, 0, stream>>>(Wf1, WF1t, 512, 2048);
  transpose_cvt_kernel<<<dim3(32, 4), 256, 0, stream>>>(Wf2, WF2t, 2048, 256);
  precM_kernel<<<16, 256, 0, stream>>>(Wq, Wk, Mt);

  if (big_ok) {
    // full-size QK GEMM + single attention launch
    mfma_gemm_kernel<0><<<dim3(T_TOK / 64, 8), 512, 0, stream>>>(
        SB, Mt, QKc, nullptr, nullptr, 256, 2048);
    attn_kernel<<<T_TOK / 4, 256, 0, stream>>>(QKc, target, weights, conf, Wv, AObf, 0);
  } else {
    for (int c = 0; c < T_TOK / CHUNK; c++) {
      int t0 = c * CHUNK;
      mfma_gemm_kernel<0><<<dim3(CHUNK / 64, 8), 512, 0, stream>>>(
          SB + (size_t)t0 * CC, Mt, QKc, nullptr, nullptr, 256, 2048);
      attn_kernel<<<CHUNK / 4, 256, 0, stream>>>(QKc, target, weights, conf, Wv, AObf, t0);
    }
  }
  // message = LN(AO @ Wm)
  mfma_gemm_kernel<1><<<dim3(T_TOK / 64, 1), 512, 0, stream>>>(
      AObf, WMt, MSGb, g1, b1, 256, 256);

  if (big_ok) {
    gemm1_kernel<<<dim3(T_TOK / 128, 16), 256, 0, stream>>>(SB, MSGb, WF1t, hid);
    gemm2_kernel<<<dim3(T_TOK / 64, 2), 256, 0, stream>>>(hid, WF2t, out);
    ln_res_kernel<<<T_TOK / 4, 256, 0, stream>>>(out, source, g2, b2);
  } else {
    ffn_mfma_kernel<<<T_TOK / 64, 512, 0, stream>>>(SB, MSGb, WF1t, WF2t, g2, b2, source, out);
  }
}

// Round 6
// 411.512 us; speedup vs baseline: 1.6185x; 1.1411x over previous
//
#include <hip/hip_runtime.h>
#include <hip/hip_bf16.h>
#include <math.h>

#define T_TOK 16384
#define CC 256
#define PP 16
#define HH 8
#define DD 32
#define LN_EPS 1e-5f

typedef __attribute__((ext_vector_type(8))) short bf16x8_t;
typedef __attribute__((ext_vector_type(4))) float f32x4_t;

__device__ __forceinline__ unsigned short f2bf(float x) {
  __hip_bfloat16 h = __float2bfloat16(x);
  return *reinterpret_cast<unsigned short*>(&h);
}
__device__ __forceinline__ float bf2f(unsigned short u) {
  union { unsigned int i; float f; } v; v.i = ((unsigned int)u) << 16; return v.f;
}

// ---------------------------------------------------------------------------
// Prep kernels
// ---------------------------------------------------------------------------
__global__ __launch_bounds__(256) void cvt_bf16_kernel(const float* __restrict__ src,
                                                       unsigned short* __restrict__ dst) {
  int i = (blockIdx.x * 256 + threadIdx.x) * 4;
  float4 v = *(const float4*)&src[i];
  ushort4 o = make_ushort4(f2bf(v.x), f2bf(v.y), f2bf(v.z), f2bf(v.w));
  *(ushort4*)&dst[i] = o;
}

__global__ __launch_bounds__(256) void transpose_cvt_kernel(const float* __restrict__ src,
                                                            unsigned short* __restrict__ dst,
                                                            int K, int N) {
  __shared__ float tile[64][65];
  int k0 = blockIdx.x * 64, n0 = blockIdx.y * 64;
  int tid = threadIdx.x;
#pragma unroll
  for (int i = 0; i < 16; i++) {
    int lin = i * 256 + tid, r = lin >> 6, c = lin & 63;
    tile[r][c] = src[(size_t)(k0 + r) * N + n0 + c];
  }
  __syncthreads();
#pragma unroll
  for (int i = 0; i < 16; i++) {
    int lin = i * 256 + tid, n = lin >> 6, k = lin & 63;
    dst[(size_t)(n0 + n) * K + k0 + k] = f2bf(tile[k][n]);
  }
}

// Mt[(h*256+e)][c] = bf16( sum_d Wq[c][h*32+d] * Wk[e][h*32+d] )
__global__ __launch_bounds__(256) void precM_kernel(const float* __restrict__ Wq,
                                                    const float* __restrict__ Wk,
                                                    unsigned short* __restrict__ Mt) {
  __shared__ float wqS[256][33];
  __shared__ float wkS[128][33];
  const int tid = threadIdx.x;
  const int h = blockIdx.x >> 1, eh = blockIdx.x & 1;
#pragma unroll
  for (int it = 0; it < 32; it++) {
    int lin = it * 256 + tid, r = lin >> 5, d = lin & 31;
    wqS[r][d] = Wq[(size_t)r * CC + h * DD + d];
  }
#pragma unroll
  for (int it = 0; it < 16; it++) {
    int lin = it * 256 + tid, r = lin >> 5, d = lin & 31;
    wkS[r][d] = Wk[(size_t)(eh * 128 + r) * CC + h * DD + d];
  }
  __syncthreads();
  const int w = tid >> 6, l = tid & 63;
  for (int ei = 0; ei < 32; ei++) {
    int e = w * 32 + ei;
    float o[4] = {0.f, 0.f, 0.f, 0.f};
#pragma unroll
    for (int d = 0; d < 32; d++) {
      float kv = wkS[e][d];
      o[0] += kv * wqS[l][d];
      o[1] += kv * wqS[l + 64][d];
      o[2] += kv * wqS[l + 128][d];
      o[3] += kv * wqS[l + 192][d];
    }
    size_t rowb = (size_t)(h * 256 + eh * 128 + e) * CC;
    Mt[rowb + l] = f2bf(o[0]);
    Mt[rowb + l + 64] = f2bf(o[1]);
    Mt[rowb + l + 128] = f2bf(o[2]);
    Mt[rowb + l + 192] = f2bf(o[3]);
  }
}

// WVMt[c][h*256+e] = bf16( sum_d Wv[e][h*32+d] * Wm[h*32+d][c] ); grid = 8 (h)
__global__ __launch_bounds__(256) void precWVM_kernel(const float* __restrict__ Wv,
                                                      const float* __restrict__ Wm,
                                                      unsigned short* __restrict__ WVMt) {
  __shared__ float WvS[256][33];
  __shared__ float WmS[32][257];
  const int h = blockIdx.x;
  const int tid = threadIdx.x;
#pragma unroll
  for (int it = 0; it < 32; it++) {
    int lin = it * 256 + tid, e = lin >> 5, d = lin & 31;
    WvS[e][d] = Wv[(size_t)e * CC + h * DD + d];
  }
#pragma unroll
  for (int it = 0; it < 32; it++) {
    int lin = it * 256 + tid, d = lin >> 8, c = lin & 255;
    WmS[d][c] = Wm[(size_t)(h * DD + d) * CC + c];
  }
  __syncthreads();
  float wm[32];
#pragma unroll
  for (int d = 0; d < 32; d++) wm[d] = WmS[d][tid];
  for (int e = 0; e < 256; e++) {
    float acc = 0.f;
#pragma unroll
    for (int d = 0; d < 32; d++) acc += WvS[e][d] * wm[d];
    WVMt[(size_t)tid * 2048 + h * 256 + e] = f2bf(acc);
  }
}

// ---------------------------------------------------------------------------
// MFMA GEMM: Out = A[M,K] @ Bt^T, BM=64 BN=256 BK=32, bf16 store.
// ---------------------------------------------------------------------------
__global__ __launch_bounds__(512) void mfma_gemm_kernel(
    const unsigned short* __restrict__ A, const unsigned short* __restrict__ Bt,
    unsigned short* __restrict__ Out, int K, int strideO) {
  __shared__ __align__(16) unsigned short As[2][64 * 32];
  __shared__ __align__(16) unsigned short Bs[2][256 * 32];
  const int tid = threadIdx.x;
  const int wv = tid >> 6, l = tid & 63;
  const int wr = wv >> 2, wc = wv & 3;
  const int lr = l & 15, lq = l >> 4;
  const int m0 = blockIdx.x * 64;
  const int n0 = blockIdx.y * 256;
  const int nsteps = K >> 5;

  f32x4_t acc[2][4];
#pragma unroll
  for (int m = 0; m < 2; m++)
#pragma unroll
    for (int n = 0; n < 4; n++) acc[m][n] = (f32x4_t){0.f, 0.f, 0.f, 0.f};

  uint4 aReg; uint4 bReg[2];
  if (tid < 256) {
    int r = tid >> 2, s = tid & 3, q = s ^ ((r >> 1) & 3);
    aReg = *(const uint4*)&A[(size_t)(m0 + r) * K + q * 8];
    *(uint4*)&As[0][r * 32 + s * 8] = aReg;
  }
#pragma unroll
  for (int it = 0; it < 2; it++) {
    int lin = it * 512 + tid, r = lin >> 2, s = lin & 3, q = s ^ ((r >> 1) & 3);
    bReg[it] = *(const uint4*)&Bt[(size_t)(n0 + r) * K + q * 8];
    *(uint4*)&Bs[0][r * 32 + s * 8] = bReg[it];
  }
  __syncthreads();

  for (int st = 0; st < nsteps; st++) {
    int cur = st & 1;
    bool pf = (st + 1) < nsteps;
    if (pf) {
      int kn = (st + 1) * 32;
      if (tid < 256) {
        int r = tid >> 2, s = tid & 3, q = s ^ ((r >> 1) & 3);
        aReg = *(const uint4*)&A[(size_t)(m0 + r) * K + kn + q * 8];
      }
#pragma unroll
      for (int it = 0; it < 2; it++) {
        int lin = it * 512 + tid, r = lin >> 2, s = lin & 3, q = s ^ ((r >> 1) & 3);
        bReg[it] = *(const uint4*)&Bt[(size_t)(n0 + r) * K + kn + q * 8];
      }
    }
    bf16x8_t af[2], bfr[4];
#pragma unroll
    for (int m = 0; m < 2; m++) {
      int r = wr * 32 + m * 16 + lr;
      int s = lq ^ ((r >> 1) & 3);
      af[m] = *(const bf16x8_t*)&As[cur][r * 32 + s * 8];
    }
#pragma unroll
    for (int n = 0; n < 4; n++) {
      int r = wc * 64 + n * 16 + lr;
      int s = lq ^ ((r >> 1) & 3);
      bfr[n] = *(const bf16x8_t*)&Bs[cur][r * 32 + s * 8];
    }
#pragma unroll
    for (int m = 0; m < 2; m++)
#pragma unroll
      for (int n = 0; n < 4; n++)
        acc[m][n] = __builtin_amdgcn_mfma_f32_16x16x32_bf16(af[m], bfr[n], acc[m][n], 0, 0, 0);
    if (pf) {
      if (tid < 256) {
        int r = tid >> 2, s = tid & 3;
        *(uint4*)&As[cur ^ 1][r * 32 + s * 8] = aReg;
      }
#pragma unroll
      for (int it = 0; it < 2; it++) {
        int lin = it * 512 + tid, r = lin >> 2, s = lin & 3;
        *(uint4*)&Bs[cur ^ 1][r * 32 + s * 8] = bReg[it];
      }
    }
    __syncthreads();
  }

#pragma unroll
  for (int m = 0; m < 2; m++)
#pragma unroll
    for (int n = 0; n < 4; n++)
#pragma unroll
      for (int j = 0; j < 4; j++) {
        int rl = wr * 32 + m * 16 + lq * 4 + j;
        int col = n0 + wc * 64 + n * 16 + lr;
        Out[(size_t)(m0 + rl) * strideO + col] = f2bf(acc[m][n][j]);
      }
}

// ---------------------------------------------------------------------------
// attn2: per wave = one token. T tile f32->bf16 staged in swizzled LDS;
// scores via 8 MFMAs; softmax on 4 regs + 2 shuffles; combine over p from
// LDS; writes TC[t][(h,e)] bf16. No __syncthreads (waves independent).
// ---------------------------------------------------------------------------
__global__ __launch_bounds__(256) void attn2_kernel(const unsigned short* __restrict__ QKc,
                                                    const float* __restrict__ target,
                                                    const float* __restrict__ wts,
                                                    const float* __restrict__ conf,
                                                    unsigned short* __restrict__ TC) {
  __shared__ __align__(16) unsigned short Ts[4][16 * 256];   // 8KB per wave, swizzled
  __shared__ float awL[4][PP][HH];
  const int tid = threadIdx.x;
  const int w = tid >> 6, l = tid & 63;
  const int t = blockIdx.x * 4 + w;
  const float* trow = target + (size_t)t * PP * CC;
  char* tsb = (char*)&Ts[w][0];

  // ---- stage T tile: p = l>>2, slots s = (l&3) + i*4; swizzle slot^(p&7) ----
  {
    const int p = l >> 2;
#pragma unroll
    for (int i = 0; i < 8; i++) {
      int s = (l & 3) + i * 4;
      const float* gp = &trow[p * CC + s * 8];
      float4 v0 = *(const float4*)gp;
      float4 v1 = *(const float4*)(gp + 4);
      ushort4 u0 = make_ushort4(f2bf(v0.x), f2bf(v0.y), f2bf(v0.z), f2bf(v0.w));
      ushort4 u1 = make_ushort4(f2bf(v1.x), f2bf(v1.y), f2bf(v1.z), f2bf(v1.w));
      uint4 pk;
      pk.x = (unsigned)u0.x | ((unsigned)u0.y << 16);
      pk.y = (unsigned)u0.z | ((unsigned)u0.w << 16);
      pk.z = (unsigned)u1.x | ((unsigned)u1.y << 16);
      pk.w = (unsigned)u1.z | ((unsigned)u1.w << 16);
      *(uint4*)(tsb + p * 512 + ((s ^ (p & 7)) << 4)) = pk;
    }
  }

  // ---- scores[p][h] via MFMA: A = T tile, B = qk row (h clamped to 0..7) ----
  f32x4_t sc4 = (f32x4_t){0.f, 0.f, 0.f, 0.f};
  {
    const int lr = l & 15, lq = l >> 4;
    const unsigned short* qkrow = QKc + (size_t)t * 2048 + (size_t)(lr & 7) * 256;
#pragma unroll
    for (int es = 0; es < 8; es++) {
      int slot = es * 4 + lq;
      bf16x8_t aF = *(const bf16x8_t*)(tsb + lr * 512 + ((slot ^ (lr & 7)) << 4));
      bf16x8_t bF = *(const bf16x8_t*)&qkrow[es * 32 + lq * 8];
      sc4 = __builtin_amdgcn_mfma_f32_16x16x32_bf16(aF, bF, sc4, 0, 0, 0);
    }
  }

  // ---- softmax over p (4 regs x 4 lane-groups) ----
  {
    const int g = l >> 4;
    const float rsD = 0.17677669529663687f;
    float sc[4], cf[4];
#pragma unroll
    for (int j = 0; j < 4; j++) {
      int p = g * 4 + j;
      sc[j] = sc4[j] * wts[(size_t)t * PP + p] * rsD;
      cf[j] = conf[(size_t)t * PP + p];
    }
    float mx = fmaxf(fmaxf(sc[0], sc[1]), fmaxf(sc[2], sc[3]));
    mx = fmaxf(mx, __shfl_xor(mx, 16, 64));
    mx = fmaxf(mx, __shfl_xor(mx, 32, 64));
    float ex[4], sm = 0.f;
#pragma unroll
    for (int j = 0; j < 4; j++) { ex[j] = expf(sc[j] - mx); sm += ex[j]; }
    sm += __shfl_xor(sm, 16, 64);
    sm += __shfl_xor(sm, 32, 64);
    float inv = 1.f / sm;
    if ((l & 15) < 8) {
#pragma unroll
      for (int j = 0; j < 4; j++) awL[w][g * 4 + j][l & 15] = ex[j] * inv * cf[j];
    }
  }

  // ---- combine: tc[h][e=4l..4l+3] = sum_p aw[p][h] * T[p][e] ----
  float tc[HH][4];
#pragma unroll
  for (int h = 0; h < HH; h++)
#pragma unroll
    for (int j = 0; j < 4; j++) tc[h][j] = 0.f;
#pragma unroll
  for (int p = 0; p < PP; p++) {
    uint2 tv = *(const uint2*)(tsb + p * 512 + (((l >> 1) ^ (p & 7)) << 4) + (l & 1) * 8);
    float te0 = bf2f((unsigned short)(tv.x & 0xffff));
    float te1 = bf2f((unsigned short)(tv.x >> 16));
    float te2 = bf2f((unsigned short)(tv.y & 0xffff));
    float te3 = bf2f((unsigned short)(tv.y >> 16));
#pragma unroll
    for (int h = 0; h < HH; h++) {
      float a = awL[w][p][h];
      tc[h][0] += a * te0; tc[h][1] += a * te1;
      tc[h][2] += a * te2; tc[h][3] += a * te3;
    }
  }
  size_t tcb = (size_t)t * 2048;
#pragma unroll
  for (int h = 0; h < HH; h++) {
    ushort4 o = make_ushort4(f2bf(tc[h][0]), f2bf(tc[h][1]), f2bf(tc[h][2]), f2bf(tc[h][3]));
    *(ushort4*)&TC[tcb + h * 256 + 4 * l] = o;
  }
}

// ---------------------------------------------------------------------------
// msg_gemm: MSG = LN( TC[16384,2048] @ WVMt^T ) -> bf16. BM=32, BN=256,
// 256 thr = 4 waves across N. K = 2048, double-buffered.
// ---------------------------------------------------------------------------
__global__ __launch_bounds__(256) void msg_gemm_kernel(
    const unsigned short* __restrict__ A, const unsigned short* __restrict__ Bt,
    unsigned short* __restrict__ Out, const float* __restrict__ gam,
    const float* __restrict__ bet) {
  __shared__ __align__(16) unsigned short As[2][32 * 32];
  __shared__ __align__(16) unsigned short Bs[2][256 * 32];
  __shared__ float redS[32][5], redQ[32][5];
  const int tid = threadIdx.x;
  const int wc = tid >> 6, l = tid & 63;
  const int lr = l & 15, lq = l >> 4;
  const int m0 = blockIdx.x * 32;
  const int K = 2048;

  f32x4_t acc[2][4];
#pragma unroll
  for (int m = 0; m < 2; m++)
#pragma unroll
    for (int n = 0; n < 4; n++) acc[m][n] = (f32x4_t){0.f, 0.f, 0.f, 0.f};

  uint4 aReg; uint4 bReg[4];
  if (tid < 128) {
    int r = tid >> 2, s = tid & 3, q = s ^ ((r >> 1) & 3);
    aReg = *(const uint4*)&A[(size_t)(m0 + r) * K + q * 8];
    *(uint4*)&As[0][r * 32 + s * 8] = aReg;
  }
#pragma unroll
  for (int it = 0; it < 4; it++) {
    int lin = it * 256 + tid, r = lin >> 2, s = lin & 3, q = s ^ ((r >> 1) & 3);
    bReg[it] = *(const uint4*)&Bt[(size_t)r * K + q * 8];
    *(uint4*)&Bs[0][r * 32 + s * 8] = bReg[it];
  }
  __syncthreads();

  for (int st = 0; st < 64; st++) {
    int cur = st & 1;
    bool pf = st < 63;
    if (pf) {
      int kn = (st + 1) * 32;
      if (tid < 128) {
        int r = tid >> 2, s = tid & 3, q = s ^ ((r >> 1) & 3);
        aReg = *(const uint4*)&A[(size_t)(m0 + r) * K + kn + q * 8];
      }
#pragma unroll
      for (int it = 0; it < 4; it++) {
        int lin = it * 256 + tid, r = lin >> 2, s = lin & 3, q = s ^ ((r >> 1) & 3);
        bReg[it] = *(const uint4*)&Bt[(size_t)r * K + kn + q * 8];
      }
    }
    bf16x8_t af[2], bfr[4];
#pragma unroll
    for (int m = 0; m < 2; m++) {
      int r = m * 16 + lr;
      int s = lq ^ ((r >> 1) & 3);
      af[m] = *(const bf16x8_t*)&As[cur][r * 32 + s * 8];
    }
#pragma unroll
    for (int n = 0; n < 4; n++) {
      int r = wc * 64 + n * 16 + lr;
      int s = lq ^ ((r >> 1) & 3);
      bfr[n] = *(const bf16x8_t*)&Bs[cur][r * 32 + s * 8];
    }
#pragma unroll
    for (int m = 0; m < 2; m++)
#pragma unroll
      for (int n = 0; n < 4; n++)
        acc[m][n] = __builtin_amdgcn_mfma_f32_16x16x32_bf16(af[m], bfr[n], acc[m][n], 0, 0, 0);
    if (pf) {
      if (tid < 128) {
        int r = tid >> 2, s = tid & 3;
        *(uint4*)&As[cur ^ 1][r * 32 + s * 8] = aReg;
      }
#pragma unroll
      for (int it = 0; it < 4; it++) {
        int lin = it * 256 + tid, r = lin >> 2, s = lin & 3;
        *(uint4*)&Bs[cur ^ 1][r * 32 + s * 8] = bReg[it];
      }
    }
    __syncthreads();
  }

  // LN epilogue
  float s1[2][4], s2[2][4];
#pragma unroll
  for (int m = 0; m < 2; m++)
#pragma unroll
    for (int j = 0; j < 4; j++) {
      float a = 0.f, b = 0.f;
#pragma unroll
      for (int n = 0; n < 4; n++) { float x = acc[m][n][j]; a += x; b += x * x; }
      s1[m][j] = a; s2[m][j] = b;
    }
#pragma unroll
  for (int mask = 1; mask < 16; mask <<= 1)
#pragma unroll
    for (int m = 0; m < 2; m++)
#pragma unroll
      for (int j = 0; j < 4; j++) {
        s1[m][j] += __shfl_xor(s1[m][j], mask, 64);
        s2[m][j] += __shfl_xor(s2[m][j], mask, 64);
      }
  if (lr == 0) {
#pragma unroll
    for (int m = 0; m < 2; m++)
#pragma unroll
      for (int j = 0; j < 4; j++) {
        int rl = m * 16 + lq * 4 + j;
        redS[rl][wc] = s1[m][j];
        redQ[rl][wc] = s2[m][j];
      }
  }
  __syncthreads();
#pragma unroll
  for (int m = 0; m < 2; m++)
#pragma unroll
    for (int j = 0; j < 4; j++) {
      int rl = m * 16 + lq * 4 + j;
      float ts = redS[rl][0] + redS[rl][1] + redS[rl][2] + redS[rl][3];
      float tq = redQ[rl][0] + redQ[rl][1] + redQ[rl][2] + redQ[rl][3];
      float mu = ts * (1.f / 256.f);
      float var = tq * (1.f / 256.f) - mu * mu;
      float rs = rsqrtf(var + LN_EPS);
#pragma unroll
      for (int n = 0; n < 4; n++) {
        int col = wc * 64 + n * 16 + lr;
        float v = (acc[m][n][j] - mu) * rs * gam[col] + bet[col];
        Out[(size_t)(m0 + rl) * CC + col] = f2bf(v);
      }
    }
}

// ---------------------------------------------------------------------------
// FFN GEMM1: hid = gelu([SB||MSG] @ W1t^T), bf16. BM=128 BN=128, 256 thr.
// ---------------------------------------------------------------------------
__global__ __launch_bounds__(256) void gemm1_kernel(
    const unsigned short* __restrict__ SB, const unsigned short* __restrict__ MSG,
    const unsigned short* __restrict__ W1t, unsigned short* __restrict__ hid) {
  __shared__ __align__(16) unsigned short As[2][128 * 32];
  __shared__ __align__(16) unsigned short Bs[2][128 * 32];
  const int tid = threadIdx.x;
  const int wv = tid >> 6, l = tid & 63;
  const int wr = wv >> 1, wc = wv & 1;
  const int lr = l & 15, lq = l >> 4;
  const int m0 = blockIdx.x * 128;
  const int n0 = blockIdx.y * 128;

  f32x4_t acc[4][4];
#pragma unroll
  for (int m = 0; m < 4; m++)
#pragma unroll
    for (int n = 0; n < 4; n++) acc[m][n] = (f32x4_t){0.f, 0.f, 0.f, 0.f};

  uint4 aR[2], bR[2];
#pragma unroll
  for (int it = 0; it < 2; it++) {
    int lin = it * 256 + tid, r = lin >> 2, s = lin & 3, q = s ^ ((r >> 1) & 3);
    aR[it] = *(const uint4*)&SB[(size_t)(m0 + r) * CC + q * 8];
    *(uint4*)&As[0][r * 32 + s * 8] = aR[it];
    bR[it] = *(const uint4*)&W1t[(size_t)(n0 + r) * 512 + q * 8];
    *(uint4*)&Bs[0][r * 32 + s * 8] = bR[it];
  }
  __syncthreads();

  for (int st = 0; st < 16; st++) {
    int cur = st & 1;
    bool pf = st < 15;
    if (pf) {
      int kn = (st + 1) * 32;
#pragma unroll
      for (int it = 0; it < 2; it++) {
        int lin = it * 256 + tid, r = lin >> 2, s = lin & 3, q = s ^ ((r >> 1) & 3);
        int ka = kn + q * 8;
        const unsigned short* ap = (ka < 256) ? &SB[(size_t)(m0 + r) * CC + ka]
                                              : &MSG[(size_t)(m0 + r) * CC + ka - 256];
        aR[it] = *(const uint4*)ap;
        bR[it] = *(const uint4*)&W1t[(size_t)(n0 + r) * 512 + kn + q * 8];
      }
    }
    bf16x8_t af[4], bf[4];
#pragma unroll
    for (int m = 0; m < 4; m++) {
      int r = wr * 64 + m * 16 + lr;
      int s = lq ^ ((r >> 1) & 3);
      af[m] = *(const bf16x8_t*)&As[cur][r * 32 + s * 8];
    }
#pragma unroll
    for (int n = 0; n < 4; n++) {
      int r = wc * 64 + n * 16 + lr;
      int s = lq ^ ((r >> 1) & 3);
      bf[n] = *(const bf16x8_t*)&Bs[cur][r * 32 + s * 8];
    }
#pragma unroll
    for (int m = 0; m < 4; m++)
#pragma unroll
      for (int n = 0; n < 4; n++)
        acc[m][n] = __builtin_amdgcn_mfma_f32_16x16x32_bf16(af[m], bf[n], acc[m][n], 0, 0, 0);
    if (pf) {
#pragma unroll
      for (int it = 0; it < 2; it++) {
        int lin = it * 256 + tid, r = lin >> 2, s = lin & 3;
        *(uint4*)&As[cur ^ 1][r * 32 + s * 8] = aR[it];
        *(uint4*)&Bs[cur ^ 1][r * 32 + s * 8] = bR[it];
      }
    }
    __syncthreads();
  }

#pragma unroll
  for (int m = 0; m < 4; m++)
#pragma unroll
    for (int n = 0; n < 4; n++)
#pragma unroll
      for (int j = 0; j < 4; j++) {
        int row = m0 + wr * 64 + m * 16 + lq * 4 + j;
        int col = n0 + wc * 64 + n * 16 + lr;
        float x = acc[m][n][j];
        float gl = 0.5f * x * (1.0f + erff(x * 0.70710678118654752f));
        hid[(size_t)row * 2048 + col] = f2bf(gl);
      }
}

// ---------------------------------------------------------------------------
// FFN GEMM2: raw = hid @ W2t^T, f32 to d_out. BM=64 BN=128, 256 thr.
// ---------------------------------------------------------------------------
__global__ __launch_bounds__(256) void gemm2_kernel(
    const unsigned short* __restrict__ hid, const unsigned short* __restrict__ W2t,
    float* __restrict__ outRaw) {
  __shared__ __align__(16) unsigned short As[2][64 * 32];
  __shared__ __align__(16) unsigned short Bs[2][128 * 32];
  const int tid = threadIdx.x;
  const int wv = tid >> 6, l = tid & 63;
  const int wr = wv >> 1, wc = wv & 1;
  const int lr = l & 15, lq = l >> 4;
  const int m0 = blockIdx.x * 64;
  const int n0 = blockIdx.y * 128;

  f32x4_t acc[2][4];
#pragma unroll
  for (int m = 0; m < 2; m++)
#pragma unroll
    for (int n = 0; n < 4; n++) acc[m][n] = (f32x4_t){0.f, 0.f, 0.f, 0.f};

  uint4 aR, bR[2];
  {
    int r = tid >> 2, s = tid & 3, q = s ^ ((r >> 1) & 3);
    aR = *(const uint4*)&hid[(size_t)(m0 + r) * 2048 + q * 8];
    *(uint4*)&As[0][r * 32 + s * 8] = aR;
  }
#pragma unroll
  for (int it = 0; it < 2; it++) {
    int lin = it * 256 + tid, r = lin >> 2, s = lin & 3, q = s ^ ((r >> 1) & 3);
    bR[it] = *(const uint4*)&W2t[(size_t)(n0 + r) * 2048 + q * 8];
    *(uint4*)&Bs[0][r * 32 + s * 8] = bR[it];
  }
  __syncthreads();

  for (int st = 0; st < 64; st++) {
    int cur = st & 1;
    bool pf = st < 63;
    if (pf) {
      int kn = (st + 1) * 32;
      {
        int r = tid >> 2, s = tid & 3, q = s ^ ((r >> 1) & 3);
        aR = *(const uint4*)&hid[(size_t)(m0 + r) * 2048 + kn + q * 8];
      }
#pragma unroll
      for (int it = 0; it < 2; it++) {
        int lin = it * 256 + tid, r = lin >> 2, s = lin & 3, q = s ^ ((r >> 1) & 3);
        bR[it] = *(const uint4*)&W2t[(size_t)(n0 + r) * 2048 + kn + q * 8];
      }
    }
    bf16x8_t af[2], bf[4];
#pragma unroll
    for (int m = 0; m < 2; m++) {
      int r = wr * 32 + m * 16 + lr;
      int s = lq ^ ((r >> 1) & 3);
      af[m] = *(const bf16x8_t*)&As[cur][r * 32 + s * 8];
    }
#pragma unroll
    for (int n = 0; n < 4; n++) {
      int r = wc * 64 + n * 16 + lr;
      int s = lq ^ ((r >> 1) & 3);
      bf[n] = *(const bf16x8_t*)&Bs[cur][r * 32 + s * 8];
    }
#pragma unroll
    for (int m = 0; m < 2; m++)
#pragma unroll
      for (int n = 0; n < 4; n++)
        acc[m][n] = __builtin_amdgcn_mfma_f32_16x16x32_bf16(af[m], bf[n], acc[m][n], 0, 0, 0);
    if (pf) {
      {
        int r = tid >> 2, s = tid & 3;
        *(uint4*)&As[cur ^ 1][r * 32 + s * 8] = aR;
      }
#pragma unroll
      for (int it = 0; it < 2; it++) {
        int lin = it * 256 + tid, r = lin >> 2, s = lin & 3;
        *(uint4*)&Bs[cur ^ 1][r * 32 + s * 8] = bR[it];
      }
    }
    __syncthreads();
  }

#pragma unroll
  for (int m = 0; m < 2; m++)
#pragma unroll
    for (int n = 0; n < 4; n++)
#pragma unroll
      for (int j = 0; j < 4; j++) {
        int row = m0 + wr * 32 + m * 16 + lq * 4 + j;
        int col = n0 + wc * 64 + n * 16 + lr;
        outRaw[(size_t)row * CC + col] = acc[m][n][j];
      }
}

// LN + residual over raw f32 rows, in place on d_out.
__global__ __launch_bounds__(256) void ln_res_kernel(float* __restrict__ y,
                                                     const float* __restrict__ src,
                                                     const float* __restrict__ g2,
                                                     const float* __restrict__ b2) {
  const int l = threadIdx.x & 63;
  const int row = blockIdx.x * 4 + (threadIdx.x >> 6);
  size_t base = (size_t)row * CC + 4 * l;
  float4 v = *(const float4*)&y[base];
  float s1 = v.x + v.y + v.z + v.w;
  float s2 = v.x * v.x + v.y * v.y + v.z * v.z + v.w * v.w;
#pragma unroll
  for (int m = 1; m < 64; m <<= 1) {
    s1 += __shfl_xor(s1, m, 64);
    s2 += __shfl_xor(s2, m, 64);
  }
  float mu = s1 * (1.f / 256.f);
  float var = s2 * (1.f / 256.f) - mu * mu;
  float rs = rsqrtf(var + LN_EPS);
  float4 g = *(const float4*)&g2[4 * l];
  float4 b = *(const float4*)&b2[4 * l];
  float4 s = *(const float4*)&src[base];
  float4 o;
  o.x = s.x + (v.x - mu) * rs * g.x + b.x;
  o.y = s.y + (v.y - mu) * rs * g.y + b.y;
  o.z = s.z + (v.z - mu) * rs * g.z + b.z;
  o.w = s.w + (v.w - mu) * rs * g.w + b.w;
  *(float4*)&y[base] = o;
}

extern "C" void kernel_launch(void* const* d_in, const int* in_sizes, int n_in,
                              void* d_out, int out_size, void* d_ws, size_t ws_size,
                              hipStream_t stream) {
  const float* source = (const float*)d_in[0];
  const float* target = (const float*)d_in[1];
  const float* weights = (const float*)d_in[2];
  const float* conf   = (const float*)d_in[3];
  const float* Wq = (const float*)d_in[4];
  const float* Wk = (const float*)d_in[5];
  const float* Wv = (const float*)d_in[6];
  const float* Wm = (const float*)d_in[7];
  const float* g1 = (const float*)d_in[8];
  const float* b1 = (const float*)d_in[9];
  const float* Wf1 = (const float*)d_in[10];
  const float* Wf2 = (const float*)d_in[11];
  const float* g2 = (const float*)d_in[12];
  const float* b2 = (const float*)d_in[13];
  float* out = (float*)d_out;

  unsigned short* SB   = (unsigned short*)d_ws;                 // [16384][256]
  unsigned short* MSGb = SB + (size_t)T_TOK * CC;               // [16384][256]
  unsigned short* Mt   = MSGb + (size_t)T_TOK * CC;             // [2048][256]
  unsigned short* WVMt = Mt + (size_t)2048 * 256;               // [256][2048]
  unsigned short* WF1t = WVMt + (size_t)256 * 2048;             // [2048][512]
  unsigned short* WF2t = WF1t + (size_t)2048 * 512;             // [256][2048]
  unsigned short* BIG1 = WF2t + (size_t)256 * 2048;             // QKc, later hid
  unsigned short* BIG2 = BIG1 + (size_t)T_TOK * 2048;           // TC
  unsigned short* QKc  = BIG1;
  unsigned short* hid  = BIG1;
  unsigned short* TC   = BIG2;

  // prep
  cvt_bf16_kernel<<<T_TOK * CC / 1024, 256, 0, stream>>>(source, SB);
  transpose_cvt_kernel<<<dim3(8, 32), 256, 0, stream>>>(Wf1, WF1t, 512, 2048);
  transpose_cvt_kernel<<<dim3(32, 4), 256, 0, stream>>>(Wf2, WF2t, 2048, 256);
  precM_kernel<<<16, 256, 0, stream>>>(Wq, Wk, Mt);
  precWVM_kernel<<<8, 256, 0, stream>>>(Wv, Wm, WVMt);

  // attention pipeline
  mfma_gemm_kernel<<<dim3(T_TOK / 64, 8), 512, 0, stream>>>(SB, Mt, QKc, 256, 2048);
  attn2_kernel<<<T_TOK / 4, 256, 0, stream>>>(QKc, target, weights, conf, TC);
  // message = LN(TC @ WVMt^T)
  msg_gemm_kernel<<<T_TOK / 32, 256, 0, stream>>>(TC, WVMt, MSGb, g1, b1);

  // FFN
  gemm1_kernel<<<dim3(T_TOK / 128, 16), 256, 0, stream>>>(SB, MSGb, WF1t, hid);
  gemm2_kernel<<<dim3(T_TOK / 64, 2), 256, 0, stream>>>(hid, WF2t, out);
  ln_res_kernel<<<T_TOK / 4, 256, 0, stream>>>(out, source, g2, b2);
}

// Round 7
// 359.730 us; speedup vs baseline: 1.8515x; 1.1439x over previous
//
#include <hip/hip_runtime.h>
#include <hip/hip_bf16.h>
#include <math.h>

#define T_TOK 16384
#define CC 256
#define PP 16
#define HH 8
#define DD 32
#define LN_EPS 1e-5f

typedef __attribute__((ext_vector_type(8))) short bf16x8_t;
typedef __attribute__((ext_vector_type(4))) float f32x4_t;

__device__ __forceinline__ unsigned short f2bf(float x) {
  __hip_bfloat16 h = __float2bfloat16(x);
  return *reinterpret_cast<unsigned short*>(&h);
}
__device__ __forceinline__ float bf2f(unsigned short u) {
  union { unsigned int i; float f; } v; v.i = ((unsigned int)u) << 16; return v.f;
}
// async global->LDS, 16B per lane; LDS dest must be wave-uniform base + lane*16
__device__ __forceinline__ void gl_lds16(const unsigned short* g, unsigned short* l) {
  __builtin_amdgcn_global_load_lds(
      (const __attribute__((address_space(1))) unsigned int*)g,
      (__attribute__((address_space(3))) unsigned int*)l, 16, 0, 0);
}

// ---------------------------------------------------------------------------
// Prep kernels
// ---------------------------------------------------------------------------
__global__ __launch_bounds__(256) void cvt_bf16_kernel(const float* __restrict__ src,
                                                       unsigned short* __restrict__ dst) {
  int i = (blockIdx.x * 256 + threadIdx.x) * 4;
  float4 v = *(const float4*)&src[i];
  ushort4 o = make_ushort4(f2bf(v.x), f2bf(v.y), f2bf(v.z), f2bf(v.w));
  *(ushort4*)&dst[i] = o;
}

__global__ __launch_bounds__(256) void transpose_cvt_kernel(const float* __restrict__ src,
                                                            unsigned short* __restrict__ dst,
                                                            int K, int N) {
  __shared__ float tile[64][65];
  int k0 = blockIdx.x * 64, n0 = blockIdx.y * 64;
  int tid = threadIdx.x;
#pragma unroll
  for (int i = 0; i < 16; i++) {
    int lin = i * 256 + tid, r = lin >> 6, c = lin & 63;
    tile[r][c] = src[(size_t)(k0 + r) * N + n0 + c];
  }
  __syncthreads();
#pragma unroll
  for (int i = 0; i < 16; i++) {
    int lin = i * 256 + tid, n = lin >> 6, k = lin & 63;
    dst[(size_t)(n0 + n) * K + k0 + k] = f2bf(tile[k][n]);
  }
}

// Mt[(h*256+e)][c] = bf16( sum_d Wq[c][h*32+d] * Wk[e][h*32+d] )
__global__ __launch_bounds__(256) void precM_kernel(const float* __restrict__ Wq,
                                                    const float* __restrict__ Wk,
                                                    unsigned short* __restrict__ Mt) {
  __shared__ float wqS[256][33];
  __shared__ float wkS[128][33];
  const int tid = threadIdx.x;
  const int h = blockIdx.x >> 1, eh = blockIdx.x & 1;
#pragma unroll
  for (int it = 0; it < 32; it++) {
    int lin = it * 256 + tid, r = lin >> 5, d = lin & 31;
    wqS[r][d] = Wq[(size_t)r * CC + h * DD + d];
  }
#pragma unroll
  for (int it = 0; it < 16; it++) {
    int lin = it * 256 + tid, r = lin >> 5, d = lin & 31;
    wkS[r][d] = Wk[(size_t)(eh * 128 + r) * CC + h * DD + d];
  }
  __syncthreads();
  const int w = tid >> 6, l = tid & 63;
  for (int ei = 0; ei < 32; ei++) {
    int e = w * 32 + ei;
    float o[4] = {0.f, 0.f, 0.f, 0.f};
#pragma unroll
    for (int d = 0; d < 32; d++) {
      float kv = wkS[e][d];
      o[0] += kv * wqS[l][d];
      o[1] += kv * wqS[l + 64][d];
      o[2] += kv * wqS[l + 128][d];
      o[3] += kv * wqS[l + 192][d];
    }
    size_t rowb = (size_t)(h * 256 + eh * 128 + e) * CC;
    Mt[rowb + l] = f2bf(o[0]);
    Mt[rowb + l + 64] = f2bf(o[1]);
    Mt[rowb + l + 128] = f2bf(o[2]);
    Mt[rowb + l + 192] = f2bf(o[3]);
  }
}

// WVMt[c][h*256+e] = bf16( sum_d Wv[e][h*32+d] * Wm[h*32+d][c] ); grid = 8 (h)
__global__ __launch_bounds__(256) void precWVM_kernel(const float* __restrict__ Wv,
                                                      const float* __restrict__ Wm,
                                                      unsigned short* __restrict__ WVMt) {
  __shared__ float WvS[256][33];
  __shared__ float WmS[32][257];
  const int h = blockIdx.x;
  const int tid = threadIdx.x;
#pragma unroll
  for (int it = 0; it < 32; it++) {
    int lin = it * 256 + tid, e = lin >> 5, d = lin & 31;
    WvS[e][d] = Wv[(size_t)e * CC + h * DD + d];
  }
#pragma unroll
  for (int it = 0; it < 32; it++) {
    int lin = it * 256 + tid, d = lin >> 8, c = lin & 255;
    WmS[d][c] = Wm[(size_t)(h * DD + d) * CC + c];
  }
  __syncthreads();
  float wm[32];
#pragma unroll
  for (int d = 0; d < 32; d++) wm[d] = WmS[d][tid];
  for (int e = 0; e < 256; e++) {
    float acc = 0.f;
#pragma unroll
    for (int d = 0; d < 32; d++) acc += WvS[e][d] * wm[d];
    WVMt[(size_t)tid * 2048 + h * 256 + e] = f2bf(acc);
  }
}

// ---------------------------------------------------------------------------
// QK GEMM: Out = A[M,256] @ Bt^T (Bt [N][256]), BM=64 BN=256 BK=32, 512 thr.
// Staging via global_load_lds (pre-swizzled global src, linear LDS dest).
// ---------------------------------------------------------------------------
__global__ __launch_bounds__(512) void qk_gemm_kernel(
    const unsigned short* __restrict__ A, const unsigned short* __restrict__ Bt,
    unsigned short* __restrict__ Out, int K, int strideO) {
  __shared__ __align__(16) unsigned short As[64 * 32];
  __shared__ __align__(16) unsigned short Bs[256 * 32];
  const int tid = threadIdx.x;
  const int wv = tid >> 6, l = tid & 63;
  const int wr = wv >> 2, wc = wv & 3;
  const int lr = l & 15, lq = l >> 4;
  const int m0 = blockIdx.x * 64;
  const int n0 = blockIdx.y * 256;
  const int nsteps = K >> 5;

  f32x4_t acc[2][4];
#pragma unroll
  for (int m = 0; m < 2; m++)
#pragma unroll
    for (int n = 0; n < 4; n++) acc[m][n] = (f32x4_t){0.f, 0.f, 0.f, 0.f};

  const int rA = tid >> 2, sA = tid & 3, qA = sA ^ ((rA >> 1) & 3);

  for (int st = 0; st < nsteps; st++) {
    int kn = st * 32;
    if (tid < 256) gl_lds16(&A[(size_t)(m0 + rA) * K + kn + qA * 8], &As[tid * 8]);
#pragma unroll
    for (int it = 0; it < 2; it++) {
      int lin = it * 512 + tid, r = lin >> 2, s = lin & 3, q = s ^ ((r >> 1) & 3);
      gl_lds16(&Bt[(size_t)(n0 + r) * K + kn + q * 8], &Bs[lin * 8]);
    }
    __syncthreads();
    bf16x8_t af[2], bfr[4];
#pragma unroll
    for (int m = 0; m < 2; m++) {
      int r = wr * 32 + m * 16 + lr;
      int s = lq ^ ((r >> 1) & 3);
      af[m] = *(const bf16x8_t*)&As[r * 32 + s * 8];
    }
#pragma unroll
    for (int n = 0; n < 4; n++) {
      int r = wc * 64 + n * 16 + lr;
      int s = lq ^ ((r >> 1) & 3);
      bfr[n] = *(const bf16x8_t*)&Bs[r * 32 + s * 8];
    }
#pragma unroll
    for (int m = 0; m < 2; m++)
#pragma unroll
      for (int n = 0; n < 4; n++)
        acc[m][n] = __builtin_amdgcn_mfma_f32_16x16x32_bf16(af[m], bfr[n], acc[m][n], 0, 0, 0);
    __syncthreads();
  }

#pragma unroll
  for (int m = 0; m < 2; m++)
#pragma unroll
    for (int n = 0; n < 4; n++)
#pragma unroll
      for (int j = 0; j < 4; j++) {
        int rl = wr * 32 + m * 16 + lq * 4 + j;
        int col = n0 + wc * 64 + n * 16 + lr;
        Out[(size_t)(m0 + rl) * strideO + col] = f2bf(acc[m][n][j]);
      }
}

// ---------------------------------------------------------------------------
// attn2: per wave = one token. Unchanged from round 6.
// ---------------------------------------------------------------------------
__global__ __launch_bounds__(256) void attn2_kernel(const unsigned short* __restrict__ QKc,
                                                    const float* __restrict__ target,
                                                    const float* __restrict__ wts,
                                                    const float* __restrict__ conf,
                                                    unsigned short* __restrict__ TC) {
  __shared__ __align__(16) unsigned short Ts[4][16 * 256];
  __shared__ float awL[4][PP][HH];
  const int tid = threadIdx.x;
  const int w = tid >> 6, l = tid & 63;
  const int t = blockIdx.x * 4 + w;
  const float* trow = target + (size_t)t * PP * CC;
  char* tsb = (char*)&Ts[w][0];

  {
    const int p = l >> 2;
#pragma unroll
    for (int i = 0; i < 8; i++) {
      int s = (l & 3) + i * 4;
      const float* gp = &trow[p * CC + s * 8];
      float4 v0 = *(const float4*)gp;
      float4 v1 = *(const float4*)(gp + 4);
      ushort4 u0 = make_ushort4(f2bf(v0.x), f2bf(v0.y), f2bf(v0.z), f2bf(v0.w));
      ushort4 u1 = make_ushort4(f2bf(v1.x), f2bf(v1.y), f2bf(v1.z), f2bf(v1.w));
      uint4 pk;
      pk.x = (unsigned)u0.x | ((unsigned)u0.y << 16);
      pk.y = (unsigned)u0.z | ((unsigned)u0.w << 16);
      pk.z = (unsigned)u1.x | ((unsigned)u1.y << 16);
      pk.w = (unsigned)u1.z | ((unsigned)u1.w << 16);
      *(uint4*)(tsb + p * 512 + ((s ^ (p & 7)) << 4)) = pk;
    }
  }

  f32x4_t sc4 = (f32x4_t){0.f, 0.f, 0.f, 0.f};
  {
    const int lr = l & 15, lq = l >> 4;
    const unsigned short* qkrow = QKc + (size_t)t * 2048 + (size_t)(lr & 7) * 256;
#pragma unroll
    for (int es = 0; es < 8; es++) {
      int slot = es * 4 + lq;
      bf16x8_t aF = *(const bf16x8_t*)(tsb + lr * 512 + ((slot ^ (lr & 7)) << 4));
      bf16x8_t bF = *(const bf16x8_t*)&qkrow[es * 32 + lq * 8];
      sc4 = __builtin_amdgcn_mfma_f32_16x16x32_bf16(aF, bF, sc4, 0, 0, 0);
    }
  }

  {
    const int g = l >> 4;
    const float rsD = 0.17677669529663687f;
    float sc[4], cf[4];
#pragma unroll
    for (int j = 0; j < 4; j++) {
      int p = g * 4 + j;
      sc[j] = sc4[j] * wts[(size_t)t * PP + p] * rsD;
      cf[j] = conf[(size_t)t * PP + p];
    }
    float mx = fmaxf(fmaxf(sc[0], sc[1]), fmaxf(sc[2], sc[3]));
    mx = fmaxf(mx, __shfl_xor(mx, 16, 64));
    mx = fmaxf(mx, __shfl_xor(mx, 32, 64));
    float ex[4], sm = 0.f;
#pragma unroll
    for (int j = 0; j < 4; j++) { ex[j] = expf(sc[j] - mx); sm += ex[j]; }
    sm += __shfl_xor(sm, 16, 64);
    sm += __shfl_xor(sm, 32, 64);
    float inv = 1.f / sm;
    if ((l & 15) < 8) {
#pragma unroll
      for (int j = 0; j < 4; j++) awL[w][g * 4 + j][l & 15] = ex[j] * inv * cf[j];
    }
  }

  float tc[HH][4];
#pragma unroll
  for (int h = 0; h < HH; h++)
#pragma unroll
    for (int j = 0; j < 4; j++) tc[h][j] = 0.f;
#pragma unroll
  for (int p = 0; p < PP; p++) {
    uint2 tv = *(const uint2*)(tsb + p * 512 + (((l >> 1) ^ (p & 7)) << 4) + (l & 1) * 8);
    float te0 = bf2f((unsigned short)(tv.x & 0xffff));
    float te1 = bf2f((unsigned short)(tv.x >> 16));
    float te2 = bf2f((unsigned short)(tv.y & 0xffff));
    float te3 = bf2f((unsigned short)(tv.y >> 16));
#pragma unroll
    for (int h = 0; h < HH; h++) {
      float a = awL[w][p][h];
      tc[h][0] += a * te0; tc[h][1] += a * te1;
      tc[h][2] += a * te2; tc[h][3] += a * te3;
    }
  }
  size_t tcb = (size_t)t * 2048;
#pragma unroll
  for (int h = 0; h < HH; h++) {
    ushort4 o = make_ushort4(f2bf(tc[h][0]), f2bf(tc[h][1]), f2bf(tc[h][2]), f2bf(tc[h][3]));
    *(ushort4*)&TC[tcb + h * 2048 / HH + 4 * l] = o;   // h*256 + 4l
  }
}

// ---------------------------------------------------------------------------
// nwide GEMM (BM=32, BN=256, K=2048): used for msg (LN->bf16) and
// ffn2 (LN+residual->f32). EPI: 0 = LN bf16 store; 1 = LN+residual f32.
// ---------------------------------------------------------------------------
template<int EPI>
__global__ __launch_bounds__(256) void nwide_gemm_kernel(
    const unsigned short* __restrict__ A, const unsigned short* __restrict__ Bt,
    unsigned short* __restrict__ OutB, float* __restrict__ OutF,
    const float* __restrict__ gam, const float* __restrict__ bet,
    const float* __restrict__ res) {
  __shared__ __align__(16) unsigned short As[32 * 32];
  __shared__ __align__(16) unsigned short Bs[256 * 32];
  __shared__ float redS[32][5], redQ[32][5];
  const int tid = threadIdx.x;
  const int wc = tid >> 6, l = tid & 63;
  const int lr = l & 15, lq = l >> 4;
  const int m0 = blockIdx.x * 32;
  const int K = 2048;

  f32x4_t acc[2][4];
#pragma unroll
  for (int m = 0; m < 2; m++)
#pragma unroll
    for (int n = 0; n < 4; n++) acc[m][n] = (f32x4_t){0.f, 0.f, 0.f, 0.f};

  const int rA = tid >> 2, sA = tid & 3, qA = sA ^ ((rA >> 1) & 3);

  for (int st = 0; st < 64; st++) {
    int kn = st * 32;
    if (tid < 128) gl_lds16(&A[(size_t)(m0 + rA) * K + kn + qA * 8], &As[tid * 8]);
#pragma unroll
    for (int it = 0; it < 4; it++) {
      int lin = it * 256 + tid, r = lin >> 2, s = lin & 3, q = s ^ ((r >> 1) & 3);
      gl_lds16(&Bt[(size_t)r * K + kn + q * 8], &Bs[lin * 8]);
    }
    __syncthreads();
    bf16x8_t af[2], bfr[4];
#pragma unroll
    for (int m = 0; m < 2; m++) {
      int r = m * 16 + lr;
      int s = lq ^ ((r >> 1) & 3);
      af[m] = *(const bf16x8_t*)&As[r * 32 + s * 8];
    }
#pragma unroll
    for (int n = 0; n < 4; n++) {
      int r = wc * 64 + n * 16 + lr;
      int s = lq ^ ((r >> 1) & 3);
      bfr[n] = *(const bf16x8_t*)&Bs[r * 32 + s * 8];
    }
#pragma unroll
    for (int m = 0; m < 2; m++)
#pragma unroll
      for (int n = 0; n < 4; n++)
        acc[m][n] = __builtin_amdgcn_mfma_f32_16x16x32_bf16(af[m], bfr[n], acc[m][n], 0, 0, 0);
    __syncthreads();
  }

  // LN epilogue (block covers the full 256-col row)
  float s1[2][4], s2[2][4];
#pragma unroll
  for (int m = 0; m < 2; m++)
#pragma unroll
    for (int j = 0; j < 4; j++) {
      float a = 0.f, b = 0.f;
#pragma unroll
      for (int n = 0; n < 4; n++) { float x = acc[m][n][j]; a += x; b += x * x; }
      s1[m][j] = a; s2[m][j] = b;
    }
#pragma unroll
  for (int mask = 1; mask < 16; mask <<= 1)
#pragma unroll
    for (int m = 0; m < 2; m++)
#pragma unroll
      for (int j = 0; j < 4; j++) {
        s1[m][j] += __shfl_xor(s1[m][j], mask, 64);
        s2[m][j] += __shfl_xor(s2[m][j], mask, 64);
      }
  if (lr == 0) {
#pragma unroll
    for (int m = 0; m < 2; m++)
#pragma unroll
      for (int j = 0; j < 4; j++) {
        int rl = m * 16 + lq * 4 + j;
        redS[rl][wc] = s1[m][j];
        redQ[rl][wc] = s2[m][j];
      }
  }
  __syncthreads();
#pragma unroll
  for (int m = 0; m < 2; m++)
#pragma unroll
    for (int j = 0; j < 4; j++) {
      int rl = m * 16 + lq * 4 + j;
      float ts = redS[rl][0] + redS[rl][1] + redS[rl][2] + redS[rl][3];
      float tq = redQ[rl][0] + redQ[rl][1] + redQ[rl][2] + redQ[rl][3];
      float mu = ts * (1.f / 256.f);
      float var = tq * (1.f / 256.f) - mu * mu;
      float rs = rsqrtf(var + LN_EPS);
      size_t rowg = (size_t)(m0 + rl);
#pragma unroll
      for (int n = 0; n < 4; n++) {
        int col = wc * 64 + n * 16 + lr;
        float v = (acc[m][n][j] - mu) * rs * gam[col] + bet[col];
        if constexpr (EPI == 0) {
          OutB[rowg * CC + col] = f2bf(v);
        } else {
          OutF[rowg * CC + col] = res[rowg * CC + col] + v;
        }
      }
    }
}

// ---------------------------------------------------------------------------
// FFN GEMM1: hid = gelu([SB||MSG] @ W1t^T), bf16. BM=128 BN=128, 256 thr.
// ---------------------------------------------------------------------------
__global__ __launch_bounds__(256) void gemm1_kernel(
    const unsigned short* __restrict__ SB, const unsigned short* __restrict__ MSG,
    const unsigned short* __restrict__ W1t, unsigned short* __restrict__ hid) {
  __shared__ __align__(16) unsigned short As[128 * 32];
  __shared__ __align__(16) unsigned short Bs[128 * 32];
  const int tid = threadIdx.x;
  const int wv = tid >> 6, l = tid & 63;
  const int wr = wv >> 1, wc = wv & 1;
  const int lr = l & 15, lq = l >> 4;
  const int m0 = blockIdx.x * 128;
  const int n0 = blockIdx.y * 128;

  f32x4_t acc[4][4];
#pragma unroll
  for (int m = 0; m < 4; m++)
#pragma unroll
    for (int n = 0; n < 4; n++) acc[m][n] = (f32x4_t){0.f, 0.f, 0.f, 0.f};

  for (int st = 0; st < 16; st++) {
    int kn = st * 32;
#pragma unroll
    for (int it = 0; it < 2; it++) {
      int lin = it * 256 + tid, r = lin >> 2, s = lin & 3, q = s ^ ((r >> 1) & 3);
      int ka = kn + q * 8;
      const unsigned short* ap = (ka < 256) ? &SB[(size_t)(m0 + r) * CC + ka]
                                            : &MSG[(size_t)(m0 + r) * CC + ka - 256];
      gl_lds16(ap, &As[lin * 8]);
      gl_lds16(&W1t[(size_t)(n0 + r) * 512 + kn + q * 8], &Bs[lin * 8]);
    }
    __syncthreads();
    bf16x8_t af[4], bf[4];
#pragma unroll
    for (int m = 0; m < 4; m++) {
      int r = wr * 64 + m * 16 + lr;
      int s = lq ^ ((r >> 1) & 3);
      af[m] = *(const bf16x8_t*)&As[r * 32 + s * 8];
    }
#pragma unroll
    for (int n = 0; n < 4; n++) {
      int r = wc * 64 + n * 16 + lr;
      int s = lq ^ ((r >> 1) & 3);
      bf[n] = *(const bf16x8_t*)&Bs[r * 32 + s * 8];
    }
#pragma unroll
    for (int m = 0; m < 4; m++)
#pragma unroll
      for (int n = 0; n < 4; n++)
        acc[m][n] = __builtin_amdgcn_mfma_f32_16x16x32_bf16(af[m], bf[n], acc[m][n], 0, 0, 0);
    __syncthreads();
  }

#pragma unroll
  for (int m = 0; m < 4; m++)
#pragma unroll
    for (int n = 0; n < 4; n++)
#pragma unroll
      for (int j = 0; j < 4; j++) {
        int row = m0 + wr * 64 + m * 16 + lq * 4 + j;
        int col = n0 + wc * 64 + n * 16 + lr;
        float x = acc[m][n][j];
        float gl = 0.5f * x * (1.0f + erff(x * 0.70710678118654752f));
        hid[(size_t)row * 2048 + col] = f2bf(gl);
      }
}

extern "C" void kernel_launch(void* const* d_in, const int* in_sizes, int n_in,
                              void* d_out, int out_size, void* d_ws, size_t ws_size,
                              hipStream_t stream) {
  const float* source = (const float*)d_in[0];
  const float* target = (const float*)d_in[1];
  const float* weights = (const float*)d_in[2];
  const float* conf   = (const float*)d_in[3];
  const float* Wq = (const float*)d_in[4];
  const float* Wk = (const float*)d_in[5];
  const float* Wv = (const float*)d_in[6];
  const float* Wm = (const float*)d_in[7];
  const float* g1 = (const float*)d_in[8];
  const float* b1 = (const float*)d_in[9];
  const float* Wf1 = (const float*)d_in[10];
  const float* Wf2 = (const float*)d_in[11];
  const float* g2 = (const float*)d_in[12];
  const float* b2 = (const float*)d_in[13];
  float* out = (float*)d_out;

  unsigned short* SB   = (unsigned short*)d_ws;                 // [16384][256]
  unsigned short* MSGb = SB + (size_t)T_TOK * CC;               // [16384][256]
  unsigned short* Mt   = MSGb + (size_t)T_TOK * CC;             // [2048][256]
  unsigned short* WVMt = Mt + (size_t)2048 * 256;               // [256][2048]
  unsigned short* WF1t = WVMt + (size_t)256 * 2048;             // [2048][512]
  unsigned short* WF2t = WF1t + (size_t)2048 * 512;             // [256][2048]
  unsigned short* BIG1 = WF2t + (size_t)256 * 2048;             // QKc, later hid
  unsigned short* BIG2 = BIG1 + (size_t)T_TOK * 2048;           // TC
  unsigned short* QKc  = BIG1;
  unsigned short* hid  = BIG1;
  unsigned short* TC   = BIG2;

  // prep
  cvt_bf16_kernel<<<T_TOK * CC / 1024, 256, 0, stream>>>(source, SB);
  transpose_cvt_kernel<<<dim3(8, 32), 256, 0, stream>>>(Wf1, WF1t, 512, 2048);
  transpose_cvt_kernel<<<dim3(32, 4), 256, 0, stream>>>(Wf2, WF2t, 2048, 256);
  precM_kernel<<<16, 256, 0, stream>>>(Wq, Wk, Mt);
  precWVM_kernel<<<8, 256, 0, stream>>>(Wv, Wm, WVMt);

  // attention pipeline
  qk_gemm_kernel<<<dim3(T_TOK / 64, 8), 512, 0, stream>>>(SB, Mt, QKc, 256, 2048);
  attn2_kernel<<<T_TOK / 4, 256, 0, stream>>>(QKc, target, weights, conf, TC);
  // message = LN(TC @ WVMt^T)
  nwide_gemm_kernel<0><<<T_TOK / 32, 256, 0, stream>>>(
      TC, WVMt, MSGb, nullptr, g1, b1, nullptr);

  // FFN
  gemm1_kernel<<<dim3(T_TOK / 128, 16), 256, 0, stream>>>(SB, MSGb, WF1t, hid);
  // out = src + LN(hid @ W2t^T)
  nwide_gemm_kernel<1><<<T_TOK / 32, 256, 0, stream>>>(
      hid, WF2t, nullptr, out, g2, b2, source);
}